// Round 10
// baseline (884.839 us; speedup 1.0000x reference)
//
#include <hip/hip_runtime.h>
#include <math.h>

#define TLEN 1024
#define DDIM 256
#define NH_  4
#define NDIM 2048
#define HN   8192
#define NCH  16
#define CHK  64
#define VP_  50304
#define SCALE_Q 0.022097086912079608f  // 2048^-0.5

typedef unsigned short u16;
typedef __attribute__((ext_vector_type(8))) short short8;
typedef __attribute__((ext_vector_type(4))) float f32x4;

#define MFMA16(a,b,c) __builtin_amdgcn_mfma_f32_16x16x32_bf16((a),(b),(c),0,0,0)

__device__ __forceinline__ float bf2f(u16 u){ return __uint_as_float(((unsigned)u)<<16); }
__device__ __forceinline__ u16 f2bf(float f){
  unsigned x = __float_as_uint(f);
  return (u16)((x + 0x7fffu + ((x>>16)&1u)) >> 16);
}
__device__ __forceinline__ float wave_sum(float v){
  #pragma unroll
  for(int o=1;o<64;o<<=1) v += __shfl_xor(v,o,64);
  return v;
}
__device__ __forceinline__ float block_sum(float v, float* tmp){
  v = wave_sum(v);
  __syncthreads();
  if((threadIdx.x&63)==0) tmp[threadIdx.x>>6]=v;
  __syncthreads();
  return tmp[0]+tmp[1]+tmp[2]+tmp[3];
}

// ---- async global->LDS staging (linear LDS layout, 16B/lane) ----
__device__ __forceinline__ void gload16(const u16* g, u16* l){
  __builtin_amdgcn_global_load_lds((const __attribute__((address_space(1))) unsigned int*)g,
                                   (__attribute__((address_space(3))) unsigned int*)l, 16, 0, 0);
}
__device__ __forceinline__ short8 frag_lin(const u16* lds, int row, int k){
  return *(const short8*)((const char*)lds + row*128 + k*2);
}
// swizzled reads (for ds_write-staged tiles)
__device__ __forceinline__ short8 frag64(const u16* lds, int row, int k){
  return *(const short8*)((const char*)lds + row*128 + ((k*2) ^ ((row&7)<<4)));
}
__device__ __forceinline__ short8 frag512(const u16* lds, int row, int k){
  return *(const short8*)((const char*)lds + row*512 + ((k*2) ^ ((row&7)<<4)));
}

// ---- merged setup: rope tables + weight cvt + embed/rmsnorm/xin0 ----
__global__ __launch_bounds__(256) void k_setup(
  const float* __restrict__ emb, const int* __restrict__ idx,
  const float* rl, const float* xl,
  const float* __restrict__ enc_w, const float* __restrict__ gate_w,
  const float* __restrict__ dec_w, const float* __restrict__ encv_w,
  u16* w_enc, u16* w_gate, u16* w_dec, u16* w_encv,
  float* cosT, float* sinT, float* x0, float* xin, u16* xin_bf){
  __shared__ float tmp[4];
  int bid = blockIdx.x, tid = threadIdx.x;
  if(bid < 1024){
    if(tid < 128){
      int t = bid, i = tid;
      float inv_freq = exp2f(-18.0f * (float)(2*i) * (1.0f/256.0f));
      float fr = (float)t * inv_freq;
      float xsc = ((float)(2*i) + 102.4f) * (1.0f/358.4f);
      float power = ((float)t - 512.0f) * (1.0f/512.0f);
      float sc = exp2f(power * log2f(xsc));
      cosT[t*128+i] = cosf(fr)*sc;
      sinT[t*128+i] = sinf(fr)*sc;
    }
  } else if(bid < 5120){
    size_t base = (size_t)(bid-1024)*2048 + tid;
    #pragma unroll
    for(int k=0;k<8;k++){
      size_t i = base + (size_t)k*256;
      int seg = (int)(i>>21); size_t off = i & 2097151;
      const float* s; u16* dst;
      if(seg==0){ s=enc_w; dst=w_enc; } else if(seg==1){ s=gate_w; dst=w_gate; }
      else if(seg==2){ s=dec_w; dst=w_dec; } else { s=encv_w; dst=w_encv; }
      dst[off] = f2bf(s[off]);
    }
  } else {
    int t = bid - 5120, d = tid;
    float v = emb[(size_t)idx[t]*DDIM + d];
    float s = block_sum(v*v, tmp);
    float o = v * rsqrtf(s*(1.0f/DDIM) + 1e-5f);
    x0[t*DDIM+d] = o;
    float xi = rl[0]*o + xl[0]*o;
    xin[t*DDIM+d] = xi; xin_bf[t*DDIM+d] = f2bf(xi);
  }
}

// ---- generic bf16 GEMM: C = A @ B^T fp32; SPLITK -> per-z partial buffer ----
template<bool SPLITK>
__global__ __launch_bounds__(256) void k_gemm(
  const u16* __restrict__ A, int lda, const u16* __restrict__ B, int ldb,
  float* __restrict__ C, int ldc, int kchunk)
{
  __shared__ __align__(16) u16 sA[128*64];
  __shared__ __align__(16) u16 sB[128*64];
  const int m0 = blockIdx.x*128, n0 = blockIdx.y*128;
  const int k0 = blockIdx.z*kchunk;
  const int tid = threadIdx.x, lane = tid&63, wv = tid>>6;
  const int wr = (wv>>1)*64, wc = (wv&1)*64;
  f32x4 acc[4][4];
  #pragma unroll
  for(int i=0;i<4;i++)
    #pragma unroll
    for(int j=0;j<4;j++) acc[i][j] = (f32x4){0.f,0.f,0.f,0.f};
  for(int kb=0; kb<kchunk; kb+=64){
    __syncthreads();
    #pragma unroll
    for(int p=0;p<4;p++){
      int r = p*32 + (tid>>3), cb = tid&7;
      int off = r*64 + cb*8;
      gload16(A + (size_t)(m0+r)*lda + k0+kb + cb*8, sA + off);
      gload16(B + (size_t)(n0+r)*ldb + k0+kb + cb*8, sB + off);
    }
    __syncthreads();
    #pragma unroll
    for(int ks=0;ks<2;ks++){
      short8 af[4], bfr[4];
      int kk = ks*32 + 8*(lane>>4);
      #pragma unroll
      for(int i=0;i<4;i++){
        af[i]  = frag_lin(sA, wr + i*16 + (lane&15), kk);
        bfr[i] = frag_lin(sB, wc + i*16 + (lane&15), kk);
      }
      #pragma unroll
      for(int i=0;i<4;i++)
        #pragma unroll
        for(int j=0;j<4;j++)
          acc[i][j] = MFMA16(af[i], bfr[j], acc[i][j]);
    }
  }
  size_t poff = SPLITK ? (size_t)blockIdx.z * (size_t)gridDim.x * 128 * ldc : 0;
  const int rb = 4*(lane>>4), cb2 = lane&15;
  #pragma unroll
  for(int i=0;i<4;i++)
    #pragma unroll
    for(int j=0;j<4;j++){
      int col = n0 + wc + j*16 + cb2;
      #pragma unroll
      for(int r=0;r<4;r++){
        int row = m0 + wr + i*16 + rb + r;
        C[poff + (size_t)row*ldc + col] = acc[i][j][r];
      }
    }
}

// ---- lm GEMM: B panel fp32 -> bf16 LDS-resident once; loop 4 M-tiles ----
__global__ __launch_bounds__(256) void k_gemm_lm(
  const u16* __restrict__ A, const float* __restrict__ Bf, float* __restrict__ C)
{
  __shared__ __align__(16) u16 sB[128*256];   // 64 KB, 512B rows, swizzled
  __shared__ __align__(16) u16 sA[128*64];    // 16 KB
  const int n0 = blockIdx.y*128, mbase = blockIdx.x*4;
  const int tid = threadIdx.x, lane = tid&63, wv = tid>>6;
  const int wr = (wv>>1)*64, wc = (wv&1)*64;
  {
    int n = tid>>1, half = tid&1;
    const float* bp = Bf + (size_t)(n0+n)*DDIM + half*128;
    #pragma unroll
    for(int s=0;s<16;s++){
      f32x4 v0 = *(const f32x4*)(bp + s*8);
      f32x4 v1 = *(const f32x4*)(bp + s*8 + 4);
      short8 w;
      #pragma unroll
      for(int e=0;e<4;e++){ w[e]=(short)f2bf(v0[e]); w[e+4]=(short)f2bf(v1[e]); }
      int k0 = half*128 + s*8;
      *(short8*)((char*)sB + n*512 + ((k0*2) ^ ((n&7)<<4))) = w;
    }
  }
  for(int mi=0; mi<4; mi++){
    int m0 = (mbase+mi)*128;
    f32x4 acc[4][4];
    #pragma unroll
    for(int i=0;i<4;i++)
      #pragma unroll
      for(int j=0;j<4;j++) acc[i][j] = (f32x4){0.f,0.f,0.f,0.f};
    for(int kb=0; kb<4; kb++){
      __syncthreads();
      #pragma unroll
      for(int p=0;p<4;p++){
        int r = p*32 + (tid>>3), cb = tid&7;
        gload16(A + (size_t)(m0+r)*DDIM + kb*64 + cb*8, sA + r*64 + cb*8);
      }
      __syncthreads();
      #pragma unroll
      for(int ks=0;ks<2;ks++){
        short8 af[4], bfr[4];
        int kk = ks*32 + 8*(lane>>4);
        #pragma unroll
        for(int i=0;i<4;i++){
          af[i]  = frag_lin(sA, wr + i*16 + (lane&15), kk);
          bfr[i] = frag512(sB, wc + i*16 + (lane&15), kb*64 + kk);
        }
        #pragma unroll
        for(int i=0;i<4;i++)
          #pragma unroll
          for(int j=0;j<4;j++)
            acc[i][j] = MFMA16(af[i], bfr[j], acc[i][j]);
      }
    }
    const int rb = 4*(lane>>4), cb2 = lane&15;
    #pragma unroll
    for(int i=0;i<4;i++)
      #pragma unroll
      for(int j=0;j<4;j++){
        int col = n0 + wc + j*16 + cb2;
        #pragma unroll
        for(int r=0;r<4;r++){
          int row = m0 + wr + i*16 + rb + r;
          C[(size_t)row*VP_ + col] = acc[i][j][r];
        }
      }
  }
}

// ---- fused enc+gate GEMM, B-panel LDS-resident, 4 M-tiles per block ----
__global__ __launch_bounds__(256) void k_gemm_eg(
  const u16* __restrict__ xin_bf, const u16* __restrict__ w_enc, const u16* __restrict__ w_gate,
  u16* __restrict__ xs, u16* __restrict__ gate)
{
  __shared__ __align__(16) u16 sB[128*256];   // 64 KB
  __shared__ __align__(16) u16 sA[128*64];
  const int yy = blockIdx.y;
  const bool isg = yy >= 64;
  const u16* B = isg ? w_gate : w_enc;
  u16* C = isg ? gate : xs;
  const float mul = isg ? (1.0f/1024.0f) : 1.0f;
  const int n0 = (yy&63)*128, mbase = blockIdx.x*4;
  const int tid = threadIdx.x, lane = tid&63, wv = tid>>6;
  const int wr = (wv>>1)*64, wc = (wv&1)*64;
  {
    int n = tid>>1, half = tid&1;
    const u16* bp = B + (size_t)(n0+n)*DDIM + half*128;
    #pragma unroll
    for(int s=0;s<16;s++){
      short8 w = *(const short8*)(bp + s*8);
      int k0 = half*128 + s*8;
      *(short8*)((char*)sB + n*512 + ((k0*2) ^ ((n&7)<<4))) = w;
    }
  }
  for(int mi=0; mi<4; mi++){
    int m0 = (mbase+mi)*128;
    f32x4 acc[4][4];
    #pragma unroll
    for(int i=0;i<4;i++)
      #pragma unroll
      for(int j=0;j<4;j++) acc[i][j] = (f32x4){0.f,0.f,0.f,0.f};
    for(int kb=0; kb<4; kb++){
      __syncthreads();
      #pragma unroll
      for(int p=0;p<4;p++){
        int r = p*32 + (tid>>3), cb = tid&7;
        gload16(xin_bf + (size_t)(m0+r)*DDIM + kb*64 + cb*8, sA + r*64 + cb*8);
      }
      __syncthreads();
      #pragma unroll
      for(int ks=0;ks<2;ks++){
        short8 af[4], bfr[4];
        int kk = ks*32 + 8*(lane>>4);
        #pragma unroll
        for(int i=0;i<4;i++){
          af[i]  = frag_lin(sA, wr + i*16 + (lane&15), kk);
          bfr[i] = frag512(sB, wc + i*16 + (lane&15), kb*64 + kk);
        }
        #pragma unroll
        for(int i=0;i<4;i++)
          #pragma unroll
          for(int j=0;j<4;j++)
            acc[i][j] = MFMA16(af[i], bfr[j], acc[i][j]);
      }
    }
    const int rb = 4*(lane>>4), cb2 = lane&15;
    #pragma unroll
    for(int i=0;i<4;i++)
      #pragma unroll
      for(int j=0;j<4;j++){
        int col = n0 + wc + j*16 + cb2;
        #pragma unroll
        for(int r=0;r<4;r++){
          int row = m0 + wr + i*16 + rb + r;
          float v = acc[i][j][r];
          float a = v>0.f ? v*v*mul : 0.f;
          C[(size_t)row*HN + col] = f2bf(a);
        }
      }
  }
}

// ---- ys GEMM, B-panel LDS-resident, 4 M-tiles per block ----
__global__ __launch_bounds__(256) void k_gemm_ys(
  const u16* __restrict__ olnp, const u16* __restrict__ wvp,
  const u16* __restrict__ xs, u16* __restrict__ xy)
{
  __shared__ __align__(16) u16 sB[128*256];   // 64 KB
  __shared__ __align__(16) u16 sA[128*64];
  const int n0 = blockIdx.y*128, h = blockIdx.z, mbase = blockIdx.x*4;
  const u16* A = olnp + (size_t)h*TLEN*DDIM;
  const u16* B = wvp  + (size_t)h*NDIM*DDIM;
  const int tid = threadIdx.x, lane = tid&63, wv = tid>>6;
  const int wr = (wv>>1)*64, wc = (wv&1)*64;
  {
    int n = tid>>1, half = tid&1;
    const u16* bp = B + (size_t)(n0+n)*DDIM + half*128;
    #pragma unroll
    for(int s=0;s<16;s++){
      short8 w = *(const short8*)(bp + s*8);
      int k0 = half*128 + s*8;
      *(short8*)((char*)sB + n*512 + ((k0*2) ^ ((n&7)<<4))) = w;
    }
  }
  for(int mi=0; mi<4; mi++){
    int m0 = (mbase+mi)*128;
    f32x4 acc[4][4];
    #pragma unroll
    for(int i=0;i<4;i++)
      #pragma unroll
      for(int j=0;j<4;j++) acc[i][j] = (f32x4){0.f,0.f,0.f,0.f};
    for(int kb=0; kb<4; kb++){
      __syncthreads();
      #pragma unroll
      for(int p=0;p<4;p++){
        int r = p*32 + (tid>>3), cb = tid&7;
        gload16(A + (size_t)(m0+r)*DDIM + kb*64 + cb*8, sA + r*64 + cb*8);
      }
      __syncthreads();
      #pragma unroll
      for(int ks=0;ks<2;ks++){
        short8 af[4], bfr[4];
        int kk = ks*32 + 8*(lane>>4);
        #pragma unroll
        for(int i=0;i<4;i++){
          af[i]  = frag_lin(sA, wr + i*16 + (lane&15), kk);
          bfr[i] = frag512(sB, wc + i*16 + (lane&15), kb*64 + kk);
        }
        #pragma unroll
        for(int i=0;i<4;i++)
          #pragma unroll
          for(int j=0;j<4;j++)
            acc[i][j] = MFMA16(af[i], bfr[j], acc[i][j]);
      }
    }
    const int rb = 4*(lane>>4), cb2 = lane&15;
    #pragma unroll
    for(int i=0;i<4;i++)
      #pragma unroll
      for(int j=0;j<4;j++){
        int col = h*NDIM + n0 + wc + j*16 + cb2;
        #pragma unroll
        for(int r=0;r<4;r++){
          int row = m0 + wr + i*16 + rb + r;
          float v = acc[i][j][r];
          float a = v>0.f ? v*v : 0.f;
          a *= bf2f(xs[(size_t)row*HN + col]);
          xy[(size_t)row*HN + col] = f2bf(a);
        }
      }
  }
}

// ---- phase A (rope + vbT fused) ----
__global__ __launch_bounds__(256) void k_phase_a(const u16* __restrict__ xs, u16* __restrict__ gate,
                          const float* __restrict__ cosT, const float* __restrict__ sinT,
                          u16* __restrict__ qg, u16* __restrict__ kgT, float* __restrict__ gle,
                          const u16* __restrict__ xin_bf, u16* __restrict__ vbT){
  __shared__ u16 s[64*DDIM];
  int c = blockIdx.y;
  if(blockIdx.x == 32){
    int tid = threadIdx.x;
    #pragma unroll
    for(int p=0;p<8;p++){
      int idx = p*256+tid; int t = idx>>5, cb = idx&31;
      *(short8*)(s + t*DDIM + cb*8) = *(const short8*)(xin_bf + ((size_t)c*CHK + t)*DDIM + cb*8);
    }
    __syncthreads();
    int d = tid;
    u16 col[64];
    #pragma unroll
    for(int t=0;t<64;t++) col[t] = s[t*DDIM + d];
    u16* dst = vbT + ((size_t)c*DDIM + d)*CHK;
    #pragma unroll
    for(int p=0;p<8;p++){
      short8 v;
      #pragma unroll
      for(int e=0;e<8;e++) v[e] = (short)col[p*8+e];
      *(short8*)(dst + p*8) = v;
    }
    return;
  }
  int j = blockIdx.x*256 + threadIdx.x;
  int h = j>>11, n = j&2047;
  int cc = j & 255;
  int ci = cc & 127;
  bool hi_ = cc >= 128;
  int poff = hi_ ? -128 : 128;
  size_t base = (size_t)c*CHK*HN + j;
  float gsum = 0.f;
  #pragma unroll
  for(int t=0;t<CHK;t++) gsum -= bf2f(gate[base + (size_t)t*HN]);
  float egsum = expf(gsum);
  u16 kv[64];
  float gc = 0.f;
  #pragma unroll
  for(int t=0;t<CHK;t++){
    size_t ix = base + (size_t)t*HN;
    gc -= bf2f(gate[ix]);
    int tt = c*CHK + t;
    float own = bf2f(xs[ix]), oth = bf2f(xs[ix + poff]);
    float cs = cosT[tt*128+ci], sn = sinT[tt*128+ci];
    float qv = hi_ ? (own*cs + oth*sn) : (own*cs - oth*sn);
    float e1 = expf(gc);
    qg[ix] = f2bf(qv * e1 * SCALE_Q);
    u16 kgv = f2bf(qv / e1);
    gate[ix] = kgv;
    kv[t] = kgv;
  }
  u16* kb = kgT + (((size_t)c*NH_ + h)*NDIM + n)*CHK;
  #pragma unroll
  for(int p=0;p<8;p++){
    short8 v;
    #pragma unroll
    for(int e=0;e<8;e++) v[e] = (short)kv[p*8+e];
    *(short8*)(kb + p*8) = v;
  }
  gle[(size_t)c*HN + j] = egsum;
}

// ---- A partials ----
__global__ __launch_bounds__(256) void k_qk_part(const u16* __restrict__ qg, const u16* __restrict__ kg,
                                                 float* __restrict__ Apart){
  int c = blockIdx.x, h = blockIdx.y, kz = blockIdx.z;
  int tid = threadIdx.x, lane = tid&63, wv = tid>>6;
  __shared__ __align__(16) u16 sQ[2][64*64], sK[2][64*64];
  const u16* qb = qg + (size_t)c*CHK*HN + h*NDIM + kz*512;
  const u16* kb = kg + (size_t)c*CHK*HN + h*NDIM + kz*512;
  f32x4 acc[4];
  #pragma unroll
  for(int j=0;j<4;j++) acc[j] = (f32x4){0.f,0.f,0.f,0.f};
  #pragma unroll
  for(int p=0;p<2;p++){
    int r = p*32 + (tid>>3), cb = tid&7;
    int off = r*64 + cb*8;
    gload16(qb + (size_t)r*HN + cb*8, sQ[0] + off);
    gload16(kb + (size_t)r*HN + cb*8, sK[0] + off);
  }
  __syncthreads();
  for(int kt=0; kt<8; kt++){
    if(kt<7){
      #pragma unroll
      for(int p=0;p<2;p++){
        int r = p*32 + (tid>>3), cb = tid&7;
        int off = r*64 + cb*8;
        gload16(qb + (kt+1)*64 + (size_t)r*HN + cb*8, sQ[(kt+1)&1] + off);
        gload16(kb + (kt+1)*64 + (size_t)r*HN + cb*8, sK[(kt+1)&1] + off);
      }
    }
    #pragma unroll
    for(int kh=0;kh<2;kh++){
      int kk = kh*32 + 8*(lane>>4);
      short8 af = frag_lin(sQ[kt&1], wv*16 + (lane&15), kk);
      #pragma unroll
      for(int j=0;j<4;j++){
        short8 b = frag_lin(sK[kt&1], j*16 + (lane&15), kk);
        acc[j] = MFMA16(af, b, acc[j]);
      }
    }
    __syncthreads();
  }
  int rb = 4*(lane>>4), cl = lane&15;
  float* ab = Apart + (size_t)kz*(NCH*NH_*4096) + ((size_t)c*NH_+h)*4096;
  #pragma unroll
  for(int j=0;j<4;j++)
    #pragma unroll
    for(int r=0;r<4;r++){
      int t = wv*16 + rb + r, s = j*16 + cl;
      ab[t*64 + s] = acc[j][r];
    }
}

// ---- pass 1: boundary states; nb 64 blocks of 32 n; pipelined double-buffer ----
__global__ __launch_bounds__(256) void k_state(const u16* __restrict__ kgT, const u16* __restrict__ vbT,
                                               const float* __restrict__ gle, u16* __restrict__ ST){
  int nb = blockIdx.x, db = blockIdx.y, h = blockIdx.z;
  int tid = threadIdx.x, lane = tid&63, wv = tid>>6;
  __shared__ __align__(16) u16 sK[2][32*64], sV[2][64*64];
  __shared__ __align__(16) u16 sD[64*32];
  int ng = nb*32;
  int r8a = tid>>3, cb = tid&7;
  f32x4 S[2];
  S[0] = (f32x4){0.f,0.f,0.f,0.f}; S[1] = (f32x4){0.f,0.f,0.f,0.f};
  gload16(kgT + (((size_t)0*NH_ + h)*NDIM + ng + r8a)*CHK + cb*8, sK[0] + r8a*64 + cb*8);
  #pragma unroll
  for(int p=0;p<2;p++){
    int r = p*32 + r8a;
    gload16(vbT + ((size_t)0*DDIM + db*64 + r)*CHK + cb*8, sV[0] + r*64 + cb*8);
  }
  int cur = 0;
  for(int c=0;c<15;c++){
    __syncthreads();
    if(c<14){
      gload16(kgT + (((size_t)(c+1)*NH_ + h)*NDIM + ng + r8a)*CHK + cb*8, sK[cur^1] + r8a*64 + cb*8);
      #pragma unroll
      for(int p=0;p<2;p++){
        int r = p*32 + r8a;
        gload16(vbT + ((size_t)(c+1)*DDIM + db*64 + r)*CHK + cb*8, sV[cur^1] + r*64 + cb*8);
      }
    }
    #pragma unroll
    for(int kh=0;kh<2;kh++){
      int kk = kh*32 + 8*(lane>>4);
      short8 af = frag_lin(sV[cur], wv*16 + (lane&15), kk);
      #pragma unroll
      for(int fn=0;fn<2;fn++){
        short8 b = frag_lin(sK[cur], fn*16 + (lane&15), kk);
        S[fn] = MFMA16(af, b, S[fn]);
      }
    }
    #pragma unroll
    for(int fn=0;fn<2;fn++){
      float gv = gle[(size_t)c*HN + h*NDIM + ng + fn*16 + (lane&15)];
      S[fn][0]*=gv; S[fn][1]*=gv; S[fn][2]*=gv; S[fn][3]*=gv;
    }
    #pragma unroll
    for(int fn=0;fn<2;fn++)
      #pragma unroll
      for(int r=0;r<4;r++){
        int d = wv*16 + 4*(lane>>4) + r, n = fn*16 + (lane&15);
        *(u16*)((char*)sD + d*64 + ((n*2) ^ (((d>>2)&3)<<4))) = f2bf(S[fn][r]);
      }
    __syncthreads();
    {
      int dl = tid>>2, seg = tid&3;
      short8 v = *(const short8*)((const char*)sD + dl*64 + ((seg*16) ^ (((dl>>2)&3)<<4)));
      *(short8*)(ST + (((size_t)c*NH_ + h)*DDIM + db*64 + dl)*NDIM + ng + seg*8) = v;
    }
    cur ^= 1;
  }
}

// ---- fused output, n-split ×2 ----
__global__ __launch_bounds__(256) void k_out(const u16* __restrict__ qg, const u16* __restrict__ ST,
                                             const float* __restrict__ Apart, const u16* __restrict__ vbT,
                                             float* __restrict__ op){
  int c = blockIdx.x, h = blockIdx.y, zz = blockIdx.z;
  int db = zz>>1, nz = zz&1;
  int tid = threadIdx.x, lane = tid&63, wv = tid>>6;
  __shared__ __align__(16) u16 sQ[2][64*64], sS[2][64*64];
  __shared__ __align__(16) u16 sAm[64*64], sV[64*64];
  const u16* stb = (c>0) ? ST + ((size_t)(c-1)*NH_ + h)*DDIM*(size_t)NDIM + (size_t)db*64*NDIM : ST;
  const u16* qb  = qg + (size_t)c*CHK*HN + h*NDIM;
  const int ktA = nz ? 15 : 0, ktB = nz ? 32 : 15;
  int r8a = tid>>3, cb = tid&7;
  f32x4 acc[4];
  #pragma unroll
  for(int j=0;j<4;j++) acc[j] = (f32x4){0.f,0.f,0.f,0.f};
  if(c>0){
    #pragma unroll
    for(int p=0;p<2;p++){
      int r = p*32 + r8a;
      gload16(qb + ktA*64 + (size_t)r*HN + cb*8, sQ[0] + r*64 + cb*8);
      gload16(stb + (size_t)r*NDIM + ktA*64 + cb*8, sS[0] + r*64 + cb*8);
    }
  }
  if(nz==0){
    size_t abase = ((size_t)c*NH_ + h)*4096;
    #pragma unroll
    for(int e=0;e<16;e++){
      int idx = e*256 + tid;
      int t = idx>>6, s = idx&63;
      float sum = Apart[abase + idx]
                + Apart[(size_t)(NCH*NH_*4096)   + abase + idx]
                + Apart[(size_t)(NCH*NH_*4096)*2 + abase + idx]
                + Apart[(size_t)(NCH*NH_*4096)*3 + abase + idx];
      *(u16*)((char*)sAm + t*128 + ((s*2)^((t&7)<<4))) = f2bf((s<=t)? sum : 0.f);
    }
    #pragma unroll
    for(int p=0;p<2;p++){
      int r = p*32 + r8a;
      gload16(vbT + ((size_t)c*DDIM + db*64 + r)*CHK + cb*8, sV + r*64 + cb*8);
    }
  }
  __syncthreads();
  if(nz==0){
    #pragma unroll
    for(int kh=0;kh<2;kh++){
      int kk = kh*32 + 8*(lane>>4);
      short8 af = frag64(sAm, wv*16 + (lane&15), kk);
      #pragma unroll
      for(int j=0;j<4;j++){
        short8 b = frag_lin(sV, j*16 + (lane&15), kk);
        acc[j] = MFMA16(af, b, acc[j]);
      }
    }
  }
  if(c>0){
    int cur = 0;
    for(int kt=ktA; kt<ktB; kt++){
      if(kt+1<ktB){
        #pragma unroll
        for(int p=0;p<2;p++){
          int r = p*32 + r8a;
          gload16(qb + (kt+1)*64 + (size_t)r*HN + cb*8, sQ[cur^1] + r*64 + cb*8);
          gload16(stb + (size_t)r*NDIM + (kt+1)*64 + cb*8, sS[cur^1] + r*64 + cb*8);
        }
      }
      #pragma unroll
      for(int kh=0;kh<2;kh++){
        int kk = kh*32 + 8*(lane>>4);
        short8 af = frag_lin(sQ[cur], wv*16 + (lane&15), kk);
        #pragma unroll
        for(int j=0;j<4;j++){
          short8 b = frag_lin(sS[cur], j*16 + (lane&15), kk);
          acc[j] = MFMA16(af, b, acc[j]);
        }
      }
      __syncthreads();
      cur ^= 1;
    }
  }
  int rb = 4*(lane>>4), cl = lane&15;
  #pragma unroll
  for(int j=0;j<4;j++){
    int d = db*64 + j*16 + cl;
    #pragma unroll
    for(int r=0;r<4;r++){
      int t = c*CHK + wv*16 + rb + r;
      op[((size_t)(nz*NH_ + h)*TLEN + t)*DDIM + d] = acc[j][r];
    }
  }
}

// ---- layernorm over d of op0+op1 -> oln bf16 ----
__global__ __launch_bounds__(256) void k_ln(const float* __restrict__ op, u16* __restrict__ oln){
  __shared__ float tmp[4];
  int t = blockIdx.x, h = blockIdx.y, d = threadIdx.x;
  size_t ix = ((size_t)h*TLEN + t)*DDIM + d;
  float v = op[ix] + op[(size_t)NH_*TLEN*DDIM + ix];
  float s1 = block_sum(v, tmp);
  float m = s1*(1.0f/DDIM);
  float cv = v - m;
  float s2 = block_sum(cv*cv, tmp);
  oln[ix] = f2bf(cv * rsqrtf(s2*(1.0f/DDIM) + 1e-5f));
}

// ---- dec epilogue ----
__global__ __launch_bounds__(256) void k_post(const float* __restrict__ ypart, float* __restrict__ xin,
                                              const float* __restrict__ x0,
                                              const float* rl, const float* xl, const float* bl,
                                              int li, u16* __restrict__ xin_bf, u16* __restrict__ xf){
  __shared__ float tmp[4];
  int t = blockIdx.x, d = threadIdx.x;
  float v = 0.f;
  #pragma unroll
  for(int z=0;z<16;z++) v += ypart[(size_t)z*TLEN*DDIM + t*DDIM + d];
  float s1 = block_sum(v, tmp);
  float m = s1*(1.0f/DDIM);
  float cvt = v - m;
  float s2 = block_sum(cvt*cvt, tmp);
  float y = cvt * rsqrtf(s2*(1.0f/DDIM) + 1e-5f);
  float xn = y + xin[t*DDIM+d];
  float s3 = block_sum(xn*xn, tmp);
  float xv = xn * rsqrtf(s3*(1.0f/DDIM) + 1e-5f);
  if(li<3){
    float xi = rl[li+1]*xv + xl[li+1]*x0[t*DDIM+d];
    xin[t*DDIM+d] = xi; xin_bf[t*DDIM+d] = f2bf(xi);
  } else {
    float fv = xv - bl[0]*x0[t*DDIM+d];
    float s4 = block_sum(fv*fv, tmp);
    xf[t*DDIM+d] = f2bf(fv * rsqrtf(s4*(1.0f/DDIM) + 1e-5f));
  }
}

extern "C" void kernel_launch(void* const* d_in, const int* in_sizes, int n_in,
                              void* d_out, int out_size, void* d_ws, size_t ws_size,
                              hipStream_t stream){
  (void)in_sizes; (void)n_in; (void)out_size; (void)ws_size;
  const float* embed_w = (const float*)d_in[0];
  const float* lm_w    = (const float*)d_in[1];
  const float* enc_w   = (const float*)d_in[2];
  const float* gate_w  = (const float*)d_in[3];
  const float* dec_w   = (const float*)d_in[4];
  const float* encv_w  = (const float*)d_in[5];
  const float* backout = (const float*)d_in[6];
  const float* rlam    = (const float*)d_in[7];
  const float* xlam    = (const float*)d_in[8];
  const int*   idx     = (const int*)d_in[9];
  float* out = (float*)d_out;

  char* p = (char*)d_ws;
  auto alloc = [&](size_t b)->char*{ char* r=p; p += (b+255)&~(size_t)255; return r; };
  float* cosT = (float*)alloc((size_t)TLEN*128*4);
  float* sinT = (float*)alloc((size_t)TLEN*128*4);
  float* x0   = (float*)alloc((size_t)TLEN*DDIM*4);
  float* xin  = (float*)alloc((size_t)TLEN*DDIM*4);
  u16* xin_bf = (u16*)alloc((size_t)TLEN*DDIM*2);
  u16* xs     = (u16*)alloc((size_t)TLEN*HN*2);        // dec partials alias this
  u16* q      = (u16*)alloc((size_t)TLEN*HN*2);        // qg, later xy
  u16* gate   = (u16*)alloc((size_t)TLEN*HN*2);        // gate -> kg (in-place)
  (void)alloc((size_t)15*NH_*DDIM*NDIM*2 - (size_t)TLEN*HN*2);  // ST extension
  u16* ST     = gate;   // live k_state..k_out (kg dead by then)
  float* ypart= (float*)xs; // live dec..post (xs dead)
  u16* kgT    = (u16*)alloc((size_t)NCH*NH_*NDIM*CHK*2);
  float* gle  = (float*)alloc((size_t)NCH*HN*4);
  u16* vbT    = (u16*)alloc((size_t)NCH*DDIM*CHK*2);
  float* Apart= (float*)alloc((size_t)4*NCH*NH_*CHK*CHK*4);
  float* op   = (float*)alloc((size_t)2*NH_*TLEN*DDIM*4);
  u16* oln    = (u16*)alloc((size_t)NH_*TLEN*DDIM*2);
  u16* xf     = (u16*)alloc((size_t)TLEN*DDIM*2);
  u16* w_enc  = (u16*)alloc((size_t)HN*DDIM*2);
  u16* w_gate = (u16*)alloc((size_t)HN*DDIM*2);
  u16* w_dec  = (u16*)alloc((size_t)DDIM*HN*2);
  u16* w_encv = (u16*)alloc((size_t)NH_*NDIM*DDIM*2);

  k_setup<<<6144,256,0,stream>>>(embed_w, idx, rlam, xlam,
                                 enc_w, gate_w, dec_w, encv_w,
                                 w_enc, w_gate, w_dec, w_encv,
                                 cosT, sinT, x0, xin, xin_bf);

  for(int li=0; li<4; li++){
    k_gemm_eg<<<dim3(2,128),256,0,stream>>>(xin_bf,w_enc,w_gate,xs,gate);
    k_phase_a<<<dim3(33,NCH),256,0,stream>>>(xs,gate,cosT,sinT,/*qg=*/q,kgT,gle,xin_bf,vbT);
    k_qk_part<<<dim3(NCH,NH_,4),256,0,stream>>>(/*qg=*/q,/*kg=*/gate,Apart);
    k_state<<<dim3(64,4,NH_),256,0,stream>>>(kgT,vbT,gle,ST);       // overwrites kg region (dead)
    k_out<<<dim3(NCH,NH_,8),256,0,stream>>>(/*qg=*/q,ST,Apart,vbT,op);
    k_ln<<<dim3(TLEN,NH_),256,0,stream>>>(op,oln);
    k_gemm_ys<<<dim3(2,16,NH_),256,0,stream>>>(oln,w_encv,xs,/*xy=*/q);  // last read of xs
    k_gemm<true><<<dim3(8,2,16),256,0,stream>>>(q,HN,w_dec,HN,ypart,DDIM,512); // writes over xs
    k_post<<<TLEN,256,0,stream>>>(ypart,xin,x0,rlam,xlam,backout,li,xin_bf,xf);
  }
  k_gemm_lm<<<dim3(2,393),256,0,stream>>>(xf, lm_w, out);
}

// Round 11
// 702.212 us; speedup vs baseline: 1.2601x; 1.2601x over previous
//
#include <hip/hip_runtime.h>
#include <math.h>

#define TLEN 1024
#define DDIM 256
#define NH_  4
#define NDIM 2048
#define HN   8192
#define NCH  16
#define CHK  64
#define VP_  50304
#define SCALE_Q 0.022097086912079608f  // 2048^-0.5

typedef unsigned short u16;
typedef __attribute__((ext_vector_type(8))) short short8;
typedef __attribute__((ext_vector_type(4))) float f32x4;

#define MFMA16(a,b,c) __builtin_amdgcn_mfma_f32_16x16x32_bf16((a),(b),(c),0,0,0)

__device__ __forceinline__ float bf2f(u16 u){ return __uint_as_float(((unsigned)u)<<16); }
__device__ __forceinline__ u16 f2bf(float f){
  unsigned x = __float_as_uint(f);
  return (u16)((x + 0x7fffu + ((x>>16)&1u)) >> 16);
}
__device__ __forceinline__ float wave_sum(float v){
  #pragma unroll
  for(int o=1;o<64;o<<=1) v += __shfl_xor(v,o,64);
  return v;
}
__device__ __forceinline__ float block_sum(float v, float* tmp){
  v = wave_sum(v);
  __syncthreads();
  if((threadIdx.x&63)==0) tmp[threadIdx.x>>6]=v;
  __syncthreads();
  return tmp[0]+tmp[1]+tmp[2]+tmp[3];
}

// ---- async global->LDS staging (linear LDS layout, 16B/lane) ----
__device__ __forceinline__ void gload16(const u16* g, u16* l){
  __builtin_amdgcn_global_load_lds((const __attribute__((address_space(1))) unsigned int*)g,
                                   (__attribute__((address_space(3))) unsigned int*)l, 16, 0, 0);
}
__device__ __forceinline__ short8 frag_lin(const u16* lds, int row, int k){
  return *(const short8*)((const char*)lds + row*128 + k*2);
}
// swizzled reads (for ds_write-staged tiles)
__device__ __forceinline__ short8 frag64(const u16* lds, int row, int k){
  return *(const short8*)((const char*)lds + row*128 + ((k*2) ^ ((row&7)<<4)));
}
__device__ __forceinline__ short8 frag512(const u16* lds, int row, int k){
  return *(const short8*)((const char*)lds + row*512 + ((k*2) ^ ((row&7)<<4)));
}

// ---- merged setup: rope tables + weight cvt + embed/rmsnorm/xin0 ----
__global__ __launch_bounds__(256) void k_setup(
  const float* __restrict__ emb, const int* __restrict__ idx,
  const float* rl, const float* xl,
  const float* __restrict__ enc_w, const float* __restrict__ gate_w,
  const float* __restrict__ dec_w, const float* __restrict__ encv_w,
  u16* w_enc, u16* w_gate, u16* w_dec, u16* w_encv,
  float* cosT, float* sinT, float* x0, float* xin, u16* xin_bf){
  __shared__ float tmp[4];
  int bid = blockIdx.x, tid = threadIdx.x;
  if(bid < 1024){
    if(tid < 128){
      int t = bid, i = tid;
      float inv_freq = exp2f(-18.0f * (float)(2*i) * (1.0f/256.0f));
      float fr = (float)t * inv_freq;
      float xsc = ((float)(2*i) + 102.4f) * (1.0f/358.4f);
      float power = ((float)t - 512.0f) * (1.0f/512.0f);
      float sc = exp2f(power * log2f(xsc));
      cosT[t*128+i] = cosf(fr)*sc;
      sinT[t*128+i] = sinf(fr)*sc;
    }
  } else if(bid < 5120){
    size_t base = (size_t)(bid-1024)*2048 + tid;
    #pragma unroll
    for(int k=0;k<8;k++){
      size_t i = base + (size_t)k*256;
      int seg = (int)(i>>21); size_t off = i & 2097151;
      const float* s; u16* dst;
      if(seg==0){ s=enc_w; dst=w_enc; } else if(seg==1){ s=gate_w; dst=w_gate; }
      else if(seg==2){ s=dec_w; dst=w_dec; } else { s=encv_w; dst=w_encv; }
      dst[off] = f2bf(s[off]);
    }
  } else {
    int t = bid - 5120, d = tid;
    float v = emb[(size_t)idx[t]*DDIM + d];
    float s = block_sum(v*v, tmp);
    float o = v * rsqrtf(s*(1.0f/DDIM) + 1e-5f);
    x0[t*DDIM+d] = o;
    float xi = rl[0]*o + xl[0]*o;
    xin[t*DDIM+d] = xi; xin_bf[t*DDIM+d] = f2bf(xi);
  }
}

// ---- generic bf16 GEMM: C = A @ B^T fp32; SPLITK -> per-z partial buffer ----
template<bool SPLITK>
__global__ __launch_bounds__(256) void k_gemm(
  const u16* __restrict__ A, int lda, const u16* __restrict__ B, int ldb,
  float* __restrict__ C, int ldc, int kchunk)
{
  __shared__ __align__(16) u16 sA[128*64];
  __shared__ __align__(16) u16 sB[128*64];
  const int m0 = blockIdx.x*128, n0 = blockIdx.y*128;
  const int k0 = blockIdx.z*kchunk;
  const int tid = threadIdx.x, lane = tid&63, wv = tid>>6;
  const int wr = (wv>>1)*64, wc = (wv&1)*64;
  f32x4 acc[4][4];
  #pragma unroll
  for(int i=0;i<4;i++)
    #pragma unroll
    for(int j=0;j<4;j++) acc[i][j] = (f32x4){0.f,0.f,0.f,0.f};
  for(int kb=0; kb<kchunk; kb+=64){
    __syncthreads();
    #pragma unroll
    for(int p=0;p<4;p++){
      int r = p*32 + (tid>>3), cb = tid&7;
      int off = r*64 + cb*8;
      gload16(A + (size_t)(m0+r)*lda + k0+kb + cb*8, sA + off);
      gload16(B + (size_t)(n0+r)*ldb + k0+kb + cb*8, sB + off);
    }
    __syncthreads();
    #pragma unroll
    for(int ks=0;ks<2;ks++){
      short8 af[4], bfr[4];
      int kk = ks*32 + 8*(lane>>4);
      #pragma unroll
      for(int i=0;i<4;i++){
        af[i]  = frag_lin(sA, wr + i*16 + (lane&15), kk);
        bfr[i] = frag_lin(sB, wc + i*16 + (lane&15), kk);
      }
      #pragma unroll
      for(int i=0;i<4;i++)
        #pragma unroll
        for(int j=0;j<4;j++)
          acc[i][j] = MFMA16(af[i], bfr[j], acc[i][j]);
    }
  }
  size_t poff = SPLITK ? (size_t)blockIdx.z * (size_t)gridDim.x * 128 * ldc : 0;
  const int rb = 4*(lane>>4), cb2 = lane&15;
  #pragma unroll
  for(int i=0;i<4;i++)
    #pragma unroll
    for(int j=0;j<4;j++){
      int col = n0 + wc + j*16 + cb2;
      #pragma unroll
      for(int r=0;r<4;r++){
        int row = m0 + wr + i*16 + rb + r;
        C[poff + (size_t)row*ldc + col] = acc[i][j][r];
      }
    }
}

// ---- lm GEMM: B panel fp32 -> bf16 LDS-resident once; loop 4 M-tiles ----
// (B is 51.5 MB fp32 from HBM: panel-reuse is a real traffic win here, unlike eg/ys.)
__global__ __launch_bounds__(256) void k_gemm_lm(
  const u16* __restrict__ A, const float* __restrict__ Bf, float* __restrict__ C)
{
  __shared__ __align__(16) u16 sB[128*256];   // 64 KB, 512B rows, swizzled
  __shared__ __align__(16) u16 sA[128*64];    // 16 KB
  const int n0 = blockIdx.y*128, mbase = blockIdx.x*4;
  const int tid = threadIdx.x, lane = tid&63, wv = tid>>6;
  const int wr = (wv>>1)*64, wc = (wv&1)*64;
  {
    int n = tid>>1, half = tid&1;
    const float* bp = Bf + (size_t)(n0+n)*DDIM + half*128;
    #pragma unroll
    for(int s=0;s<16;s++){
      f32x4 v0 = *(const f32x4*)(bp + s*8);
      f32x4 v1 = *(const f32x4*)(bp + s*8 + 4);
      short8 w;
      #pragma unroll
      for(int e=0;e<4;e++){ w[e]=(short)f2bf(v0[e]); w[e+4]=(short)f2bf(v1[e]); }
      int k0 = half*128 + s*8;
      *(short8*)((char*)sB + n*512 + ((k0*2) ^ ((n&7)<<4))) = w;
    }
  }
  for(int mi=0; mi<4; mi++){
    int m0 = (mbase+mi)*128;
    f32x4 acc[4][4];
    #pragma unroll
    for(int i=0;i<4;i++)
      #pragma unroll
      for(int j=0;j<4;j++) acc[i][j] = (f32x4){0.f,0.f,0.f,0.f};
    for(int kb=0; kb<4; kb++){
      __syncthreads();
      #pragma unroll
      for(int p=0;p<4;p++){
        int r = p*32 + (tid>>3), cb = tid&7;
        gload16(A + (size_t)(m0+r)*DDIM + kb*64 + cb*8, sA + r*64 + cb*8);
      }
      __syncthreads();
      #pragma unroll
      for(int ks=0;ks<2;ks++){
        short8 af[4], bfr[4];
        int kk = ks*32 + 8*(lane>>4);
        #pragma unroll
        for(int i=0;i<4;i++){
          af[i]  = frag_lin(sA, wr + i*16 + (lane&15), kk);
          bfr[i] = frag512(sB, wc + i*16 + (lane&15), kb*64 + kk);
        }
        #pragma unroll
        for(int i=0;i<4;i++)
          #pragma unroll
          for(int j=0;j<4;j++)
            acc[i][j] = MFMA16(af[i], bfr[j], acc[i][j]);
      }
    }
    const int rb = 4*(lane>>4), cb2 = lane&15;
    #pragma unroll
    for(int i=0;i<4;i++)
      #pragma unroll
      for(int j=0;j<4;j++){
        int col = n0 + wc + j*16 + cb2;
        #pragma unroll
        for(int r=0;r<4;r++){
          int row = m0 + wr + i*16 + rb + r;
          C[(size_t)row*VP_ + col] = acc[i][j][r];
        }
      }
  }
}

// ---- fused enc+gate GEMM (round-9 form: 128x128 tile, high TLP; B is L2-resident) ----
__global__ __launch_bounds__(256) void k_gemm_eg(
  const u16* __restrict__ xin_bf, const u16* __restrict__ w_enc, const u16* __restrict__ w_gate,
  u16* __restrict__ xs, u16* __restrict__ gate)
{
  __shared__ __align__(16) u16 sA[128*64];
  __shared__ __align__(16) u16 sB[128*64];
  const int yy = blockIdx.y;
  const bool isg = yy >= 64;
  const u16* B = isg ? w_gate : w_enc;
  u16* C = isg ? gate : xs;
  const float mul = isg ? (1.0f/1024.0f) : 1.0f;
  const int m0 = blockIdx.x*128, n0 = (yy&63)*128;
  const int tid = threadIdx.x, lane = tid&63, wv = tid>>6;
  const int wr = (wv>>1)*64, wc = (wv&1)*64;
  f32x4 acc[4][4];
  #pragma unroll
  for(int i=0;i<4;i++)
    #pragma unroll
    for(int j=0;j<4;j++) acc[i][j] = (f32x4){0.f,0.f,0.f,0.f};
  for(int kb=0; kb<DDIM; kb+=64){
    __syncthreads();
    #pragma unroll
    for(int p=0;p<4;p++){
      int r = p*32 + (tid>>3), cb = tid&7;
      int off = r*64 + cb*8;
      gload16(xin_bf + (size_t)(m0+r)*DDIM + kb + cb*8, sA + off);
      gload16(B + (size_t)(n0+r)*DDIM + kb + cb*8, sB + off);
    }
    __syncthreads();
    #pragma unroll
    for(int ks=0;ks<2;ks++){
      short8 af[4], bfr[4];
      int kk = ks*32 + 8*(lane>>4);
      #pragma unroll
      for(int i=0;i<4;i++){
        af[i]  = frag_lin(sA, wr + i*16 + (lane&15), kk);
        bfr[i] = frag_lin(sB, wc + i*16 + (lane&15), kk);
      }
      #pragma unroll
      for(int i=0;i<4;i++)
        #pragma unroll
        for(int j=0;j<4;j++)
          acc[i][j] = MFMA16(af[i], bfr[j], acc[i][j]);
    }
  }
  const int rb = 4*(lane>>4), cb2 = lane&15;
  #pragma unroll
  for(int i=0;i<4;i++)
    #pragma unroll
    for(int j=0;j<4;j++){
      int col = n0 + wc + j*16 + cb2;
      #pragma unroll
      for(int r=0;r<4;r++){
        int row = m0 + wr + i*16 + rb + r;
        float v = acc[i][j][r];
        float a = v>0.f ? v*v*mul : 0.f;
        C[(size_t)row*HN + col] = f2bf(a);
      }
    }
}

// ---- ys GEMM, batched over heads (round-9 form) ----
__global__ __launch_bounds__(256) void k_gemm_ys(
  const u16* __restrict__ olnp, const u16* __restrict__ wvp,
  const u16* __restrict__ xs, u16* __restrict__ xy)
{
  __shared__ __align__(16) u16 sA[128*64];
  __shared__ __align__(16) u16 sB[128*64];
  const int m0 = blockIdx.x*128, n0 = blockIdx.y*128, h = blockIdx.z;
  const u16* A = olnp + (size_t)h*TLEN*DDIM;
  const u16* B = wvp  + (size_t)h*NDIM*DDIM;
  const int tid = threadIdx.x, lane = tid&63, wv = tid>>6;
  const int wr = (wv>>1)*64, wc = (wv&1)*64;
  f32x4 acc[4][4];
  #pragma unroll
  for(int i=0;i<4;i++)
    #pragma unroll
    for(int j=0;j<4;j++) acc[i][j] = (f32x4){0.f,0.f,0.f,0.f};
  for(int kb=0; kb<DDIM; kb+=64){
    __syncthreads();
    #pragma unroll
    for(int p=0;p<4;p++){
      int r = p*32 + (tid>>3), cb = tid&7;
      int off = r*64 + cb*8;
      gload16(A + (size_t)(m0+r)*DDIM + kb + cb*8, sA + off);
      gload16(B + (size_t)(n0+r)*DDIM + kb + cb*8, sB + off);
    }
    __syncthreads();
    #pragma unroll
    for(int ks=0;ks<2;ks++){
      short8 af[4], bfr[4];
      int kk = ks*32 + 8*(lane>>4);
      #pragma unroll
      for(int i=0;i<4;i++){
        af[i]  = frag_lin(sA, wr + i*16 + (lane&15), kk);
        bfr[i] = frag_lin(sB, wc + i*16 + (lane&15), kk);
      }
      #pragma unroll
      for(int i=0;i<4;i++)
        #pragma unroll
        for(int j=0;j<4;j++)
          acc[i][j] = MFMA16(af[i], bfr[j], acc[i][j]);
    }
  }
  const int rb = 4*(lane>>4), cb2 = lane&15;
  #pragma unroll
  for(int i=0;i<4;i++)
    #pragma unroll
    for(int j=0;j<4;j++){
      int col = h*NDIM + n0 + wc + j*16 + cb2;
      #pragma unroll
      for(int r=0;r<4;r++){
        int row = m0 + wr + i*16 + rb + r;
        float v = acc[i][j][r];
        float a = v>0.f ? v*v : 0.f;
        a *= bf2f(xs[(size_t)row*HN + col]);
        xy[(size_t)row*HN + col] = f2bf(a);
      }
    }
}

// ---- phase A (rope + vbT fused) ----
__global__ __launch_bounds__(256) void k_phase_a(const u16* __restrict__ xs, u16* __restrict__ gate,
                          const float* __restrict__ cosT, const float* __restrict__ sinT,
                          u16* __restrict__ qg, u16* __restrict__ kgT, float* __restrict__ gle,
                          const u16* __restrict__ xin_bf, u16* __restrict__ vbT){
  __shared__ u16 s[64*DDIM];
  int c = blockIdx.y;
  if(blockIdx.x == 32){
    int tid = threadIdx.x;
    #pragma unroll
    for(int p=0;p<8;p++){
      int idx = p*256+tid; int t = idx>>5, cb = idx&31;
      *(short8*)(s + t*DDIM + cb*8) = *(const short8*)(xin_bf + ((size_t)c*CHK + t)*DDIM + cb*8);
    }
    __syncthreads();
    int d = tid;
    u16 col[64];
    #pragma unroll
    for(int t=0;t<64;t++) col[t] = s[t*DDIM + d];
    u16* dst = vbT + ((size_t)c*DDIM + d)*CHK;
    #pragma unroll
    for(int p=0;p<8;p++){
      short8 v;
      #pragma unroll
      for(int e=0;e<8;e++) v[e] = (short)col[p*8+e];
      *(short8*)(dst + p*8) = v;
    }
    return;
  }
  int j = blockIdx.x*256 + threadIdx.x;
  int h = j>>11, n = j&2047;
  int cc = j & 255;
  int ci = cc & 127;
  bool hi_ = cc >= 128;
  int poff = hi_ ? -128 : 128;
  size_t base = (size_t)c*CHK*HN + j;
  float gsum = 0.f;
  #pragma unroll
  for(int t=0;t<CHK;t++) gsum -= bf2f(gate[base + (size_t)t*HN]);
  float egsum = expf(gsum);
  u16 kv[64];
  float gc = 0.f;
  #pragma unroll
  for(int t=0;t<CHK;t++){
    size_t ix = base + (size_t)t*HN;
    gc -= bf2f(gate[ix]);
    int tt = c*CHK + t;
    float own = bf2f(xs[ix]), oth = bf2f(xs[ix + poff]);
    float cs = cosT[tt*128+ci], sn = sinT[tt*128+ci];
    float qv = hi_ ? (own*cs + oth*sn) : (own*cs - oth*sn);
    float e1 = expf(gc);
    qg[ix] = f2bf(qv * e1 * SCALE_Q);
    u16 kgv = f2bf(qv / e1);
    gate[ix] = kgv;
    kv[t] = kgv;
  }
  u16* kb = kgT + (((size_t)c*NH_ + h)*NDIM + n)*CHK;
  #pragma unroll
  for(int p=0;p<8;p++){
    short8 v;
    #pragma unroll
    for(int e=0;e<8;e++) v[e] = (short)kv[p*8+e];
    *(short8*)(kb + p*8) = v;
  }
  gle[(size_t)c*HN + j] = egsum;
}

// ---- A partials ----
__global__ __launch_bounds__(256) void k_qk_part(const u16* __restrict__ qg, const u16* __restrict__ kg,
                                                 float* __restrict__ Apart){
  int c = blockIdx.x, h = blockIdx.y, kz = blockIdx.z;
  int tid = threadIdx.x, lane = tid&63, wv = tid>>6;
  __shared__ __align__(16) u16 sQ[2][64*64], sK[2][64*64];
  const u16* qb = qg + (size_t)c*CHK*HN + h*NDIM + kz*512;
  const u16* kb = kg + (size_t)c*CHK*HN + h*NDIM + kz*512;
  f32x4 acc[4];
  #pragma unroll
  for(int j=0;j<4;j++) acc[j] = (f32x4){0.f,0.f,0.f,0.f};
  #pragma unroll
  for(int p=0;p<2;p++){
    int r = p*32 + (tid>>3), cb = tid&7;
    int off = r*64 + cb*8;
    gload16(qb + (size_t)r*HN + cb*8, sQ[0] + off);
    gload16(kb + (size_t)r*HN + cb*8, sK[0] + off);
  }
  __syncthreads();
  for(int kt=0; kt<8; kt++){
    if(kt<7){
      #pragma unroll
      for(int p=0;p<2;p++){
        int r = p*32 + (tid>>3), cb = tid&7;
        int off = r*64 + cb*8;
        gload16(qb + (kt+1)*64 + (size_t)r*HN + cb*8, sQ[(kt+1)&1] + off);
        gload16(kb + (kt+1)*64 + (size_t)r*HN + cb*8, sK[(kt+1)&1] + off);
      }
    }
    #pragma unroll
    for(int kh=0;kh<2;kh++){
      int kk = kh*32 + 8*(lane>>4);
      short8 af = frag_lin(sQ[kt&1], wv*16 + (lane&15), kk);
      #pragma unroll
      for(int j=0;j<4;j++){
        short8 b = frag_lin(sK[kt&1], j*16 + (lane&15), kk);
        acc[j] = MFMA16(af, b, acc[j]);
      }
    }
    __syncthreads();
  }
  int rb = 4*(lane>>4), cl = lane&15;
  float* ab = Apart + (size_t)kz*(NCH*NH_*4096) + ((size_t)c*NH_+h)*4096;
  #pragma unroll
  for(int j=0;j<4;j++)
    #pragma unroll
    for(int r=0;r<4;r++){
      int t = wv*16 + rb + r, s = j*16 + cl;
      ab[t*64 + s] = acc[j][r];
    }
}

// ---- pass 1: boundary states; nb 64 blocks of 32 n; pipelined double-buffer ----
__global__ __launch_bounds__(256) void k_state(const u16* __restrict__ kgT, const u16* __restrict__ vbT,
                                               const float* __restrict__ gle, u16* __restrict__ ST){
  int nb = blockIdx.x, db = blockIdx.y, h = blockIdx.z;
  int tid = threadIdx.x, lane = tid&63, wv = tid>>6;
  __shared__ __align__(16) u16 sK[2][32*64], sV[2][64*64];
  __shared__ __align__(16) u16 sD[64*32];
  int ng = nb*32;
  int r8a = tid>>3, cb = tid&7;
  f32x4 S[2];
  S[0] = (f32x4){0.f,0.f,0.f,0.f}; S[1] = (f32x4){0.f,0.f,0.f,0.f};
  gload16(kgT + (((size_t)0*NH_ + h)*NDIM + ng + r8a)*CHK + cb*8, sK[0] + r8a*64 + cb*8);
  #pragma unroll
  for(int p=0;p<2;p++){
    int r = p*32 + r8a;
    gload16(vbT + ((size_t)0*DDIM + db*64 + r)*CHK + cb*8, sV[0] + r*64 + cb*8);
  }
  int cur = 0;
  for(int c=0;c<15;c++){
    __syncthreads();
    if(c<14){
      gload16(kgT + (((size_t)(c+1)*NH_ + h)*NDIM + ng + r8a)*CHK + cb*8, sK[cur^1] + r8a*64 + cb*8);
      #pragma unroll
      for(int p=0;p<2;p++){
        int r = p*32 + r8a;
        gload16(vbT + ((size_t)(c+1)*DDIM + db*64 + r)*CHK + cb*8, sV[cur^1] + r*64 + cb*8);
      }
    }
    #pragma unroll
    for(int kh=0;kh<2;kh++){
      int kk = kh*32 + 8*(lane>>4);
      short8 af = frag_lin(sV[cur], wv*16 + (lane&15), kk);
      #pragma unroll
      for(int fn=0;fn<2;fn++){
        short8 b = frag_lin(sK[cur], fn*16 + (lane&15), kk);
        S[fn] = MFMA16(af, b, S[fn]);
      }
    }
    #pragma unroll
    for(int fn=0;fn<2;fn++){
      float gv = gle[(size_t)c*HN + h*NDIM + ng + fn*16 + (lane&15)];
      S[fn][0]*=gv; S[fn][1]*=gv; S[fn][2]*=gv; S[fn][3]*=gv;
    }
    #pragma unroll
    for(int fn=0;fn<2;fn++)
      #pragma unroll
      for(int r=0;r<4;r++){
        int d = wv*16 + 4*(lane>>4) + r, n = fn*16 + (lane&15);
        *(u16*)((char*)sD + d*64 + ((n*2) ^ (((d>>2)&3)<<4))) = f2bf(S[fn][r]);
      }
    __syncthreads();
    {
      int dl = tid>>2, seg = tid&3;
      short8 v = *(const short8*)((const char*)sD + dl*64 + ((seg*16) ^ (((dl>>2)&3)<<4)));
      *(short8*)(ST + (((size_t)c*NH_ + h)*DDIM + db*64 + dl)*NDIM + ng + seg*8) = v;
    }
    cur ^= 1;
  }
}

// ---- fused output, n-split ×2 ----
__global__ __launch_bounds__(256) void k_out(const u16* __restrict__ qg, const u16* __restrict__ ST,
                                             const float* __restrict__ Apart, const u16* __restrict__ vbT,
                                             float* __restrict__ op){
  int c = blockIdx.x, h = blockIdx.y, zz = blockIdx.z;
  int db = zz>>1, nz = zz&1;
  int tid = threadIdx.x, lane = tid&63, wv = tid>>6;
  __shared__ __align__(16) u16 sQ[2][64*64], sS[2][64*64];
  __shared__ __align__(16) u16 sAm[64*64], sV[64*64];
  const u16* stb = (c>0) ? ST + ((size_t)(c-1)*NH_ + h)*DDIM*(size_t)NDIM + (size_t)db*64*NDIM : ST;
  const u16* qb  = qg + (size_t)c*CHK*HN + h*NDIM;
  const int ktA = nz ? 15 : 0, ktB = nz ? 32 : 15;
  int r8a = tid>>3, cb = tid&7;
  f32x4 acc[4];
  #pragma unroll
  for(int j=0;j<4;j++) acc[j] = (f32x4){0.f,0.f,0.f,0.f};
  if(c>0){
    #pragma unroll
    for(int p=0;p<2;p++){
      int r = p*32 + r8a;
      gload16(qb + ktA*64 + (size_t)r*HN + cb*8, sQ[0] + r*64 + cb*8);
      gload16(stb + (size_t)r*NDIM + ktA*64 + cb*8, sS[0] + r*64 + cb*8);
    }
  }
  if(nz==0){
    size_t abase = ((size_t)c*NH_ + h)*4096;
    #pragma unroll
    for(int e=0;e<16;e++){
      int idx = e*256 + tid;
      int t = idx>>6, s = idx&63;
      float sum = Apart[abase + idx]
                + Apart[(size_t)(NCH*NH_*4096)   + abase + idx]
                + Apart[(size_t)(NCH*NH_*4096)*2 + abase + idx]
                + Apart[(size_t)(NCH*NH_*4096)*3 + abase + idx];
      *(u16*)((char*)sAm + t*128 + ((s*2)^((t&7)<<4))) = f2bf((s<=t)? sum : 0.f);
    }
    #pragma unroll
    for(int p=0;p<2;p++){
      int r = p*32 + r8a;
      gload16(vbT + ((size_t)c*DDIM + db*64 + r)*CHK + cb*8, sV + r*64 + cb*8);
    }
  }
  __syncthreads();
  if(nz==0){
    #pragma unroll
    for(int kh=0;kh<2;kh++){
      int kk = kh*32 + 8*(lane>>4);
      short8 af = frag64(sAm, wv*16 + (lane&15), kk);
      #pragma unroll
      for(int j=0;j<4;j++){
        short8 b = frag_lin(sV, j*16 + (lane&15), kk);
        acc[j] = MFMA16(af, b, acc[j]);
      }
    }
  }
  if(c>0){
    int cur = 0;
    for(int kt=ktA; kt<ktB; kt++){
      if(kt+1<ktB){
        #pragma unroll
        for(int p=0;p<2;p++){
          int r = p*32 + r8a;
          gload16(qb + (kt+1)*64 + (size_t)r*HN + cb*8, sQ[cur^1] + r*64 + cb*8);
          gload16(stb + (size_t)r*NDIM + (kt+1)*64 + cb*8, sS[cur^1] + r*64 + cb*8);
        }
      }
      #pragma unroll
      for(int kh=0;kh<2;kh++){
        int kk = kh*32 + 8*(lane>>4);
        short8 af = frag_lin(sQ[cur], wv*16 + (lane&15), kk);
        #pragma unroll
        for(int j=0;j<4;j++){
          short8 b = frag_lin(sS[cur], j*16 + (lane&15), kk);
          acc[j] = MFMA16(af, b, acc[j]);
        }
      }
      __syncthreads();
      cur ^= 1;
    }
  }
  int rb = 4*(lane>>4), cl = lane&15;
  #pragma unroll
  for(int j=0;j<4;j++){
    int d = db*64 + j*16 + cl;
    #pragma unroll
    for(int r=0;r<4;r++){
      int t = c*CHK + wv*16 + rb + r;
      op[((size_t)(nz*NH_ + h)*TLEN + t)*DDIM + d] = acc[j][r];
    }
  }
}

// ---- layernorm over d of op0+op1 -> oln bf16 ----
__global__ __launch_bounds__(256) void k_ln(const float* __restrict__ op, u16* __restrict__ oln){
  __shared__ float tmp[4];
  int t = blockIdx.x, h = blockIdx.y, d = threadIdx.x;
  size_t ix = ((size_t)h*TLEN + t)*DDIM + d;
  float v = op[ix] + op[(size_t)NH_*TLEN*DDIM + ix];
  float s1 = block_sum(v, tmp);
  float m = s1*(1.0f/DDIM);
  float cv = v - m;
  float s2 = block_sum(cv*cv, tmp);
  oln[ix] = f2bf(cv * rsqrtf(s2*(1.0f/DDIM) + 1e-5f));
}

// ---- dec epilogue ----
__global__ __launch_bounds__(256) void k_post(const float* __restrict__ ypart, float* __restrict__ xin,
                                              const float* __restrict__ x0,
                                              const float* rl, const float* xl, const float* bl,
                                              int li, u16* __restrict__ xin_bf, u16* __restrict__ xf){
  __shared__ float tmp[4];
  int t = blockIdx.x, d = threadIdx.x;
  float v = 0.f;
  #pragma unroll
  for(int z=0;z<16;z++) v += ypart[(size_t)z*TLEN*DDIM + t*DDIM + d];
  float s1 = block_sum(v, tmp);
  float m = s1*(1.0f/DDIM);
  float cvt = v - m;
  float s2 = block_sum(cvt*cvt, tmp);
  float y = cvt * rsqrtf(s2*(1.0f/DDIM) + 1e-5f);
  float xn = y + xin[t*DDIM+d];
  float s3 = block_sum(xn*xn, tmp);
  float xv = xn * rsqrtf(s3*(1.0f/DDIM) + 1e-5f);
  if(li<3){
    float xi = rl[li+1]*xv + xl[li+1]*x0[t*DDIM+d];
    xin[t*DDIM+d] = xi; xin_bf[t*DDIM+d] = f2bf(xi);
  } else {
    float fv = xv - bl[0]*x0[t*DDIM+d];
    float s4 = block_sum(fv*fv, tmp);
    xf[t*DDIM+d] = f2bf(fv * rsqrtf(s4*(1.0f/DDIM) + 1e-5f));
  }
}

extern "C" void kernel_launch(void* const* d_in, const int* in_sizes, int n_in,
                              void* d_out, int out_size, void* d_ws, size_t ws_size,
                              hipStream_t stream){
  (void)in_sizes; (void)n_in; (void)out_size; (void)ws_size;
  const float* embed_w = (const float*)d_in[0];
  const float* lm_w    = (const float*)d_in[1];
  const float* enc_w   = (const float*)d_in[2];
  const float* gate_w  = (const float*)d_in[3];
  const float* dec_w   = (const float*)d_in[4];
  const float* encv_w  = (const float*)d_in[5];
  const float* backout = (const float*)d_in[6];
  const float* rlam    = (const float*)d_in[7];
  const float* xlam    = (const float*)d_in[8];
  const int*   idx     = (const int*)d_in[9];
  float* out = (float*)d_out;

  char* p = (char*)d_ws;
  auto alloc = [&](size_t b)->char*{ char* r=p; p += (b+255)&~(size_t)255; return r; };
  float* cosT = (float*)alloc((size_t)TLEN*128*4);
  float* sinT = (float*)alloc((size_t)TLEN*128*4);
  float* x0   = (float*)alloc((size_t)TLEN*DDIM*4);
  float* xin  = (float*)alloc((size_t)TLEN*DDIM*4);
  u16* xin_bf = (u16*)alloc((size_t)TLEN*DDIM*2);
  u16* xs     = (u16*)alloc((size_t)TLEN*HN*2);        // dec partials alias this
  u16* q      = (u16*)alloc((size_t)TLEN*HN*2);        // qg, later xy
  u16* gate   = (u16*)alloc((size_t)TLEN*HN*2);        // gate -> kg (in-place)
  (void)alloc((size_t)15*NH_*DDIM*NDIM*2 - (size_t)TLEN*HN*2);  // ST extension
  u16* ST     = gate;   // live k_state..k_out (kg dead by then)
  float* ypart= (float*)xs; // live dec..post (xs dead)
  u16* kgT    = (u16*)alloc((size_t)NCH*NH_*NDIM*CHK*2);
  float* gle  = (float*)alloc((size_t)NCH*HN*4);
  u16* vbT    = (u16*)alloc((size_t)NCH*DDIM*CHK*2);
  float* Apart= (float*)alloc((size_t)4*NCH*NH_*CHK*CHK*4);
  float* op   = (float*)alloc((size_t)2*NH_*TLEN*DDIM*4);
  u16* oln    = (u16*)alloc((size_t)NH_*TLEN*DDIM*2);
  u16* xf     = (u16*)alloc((size_t)TLEN*DDIM*2);
  u16* w_enc  = (u16*)alloc((size_t)HN*DDIM*2);
  u16* w_gate = (u16*)alloc((size_t)HN*DDIM*2);
  u16* w_dec  = (u16*)alloc((size_t)DDIM*HN*2);
  u16* w_encv = (u16*)alloc((size_t)NH_*NDIM*DDIM*2);

  k_setup<<<6144,256,0,stream>>>(embed_w, idx, rlam, xlam,
                                 enc_w, gate_w, dec_w, encv_w,
                                 w_enc, w_gate, w_dec, w_encv,
                                 cosT, sinT, x0, xin, xin_bf);

  for(int li=0; li<4; li++){
    k_gemm_eg<<<dim3(8,128),256,0,stream>>>(xin_bf,w_enc,w_gate,xs,gate);
    k_phase_a<<<dim3(33,NCH),256,0,stream>>>(xs,gate,cosT,sinT,/*qg=*/q,kgT,gle,xin_bf,vbT);
    k_qk_part<<<dim3(NCH,NH_,4),256,0,stream>>>(/*qg=*/q,/*kg=*/gate,Apart);
    k_state<<<dim3(64,4,NH_),256,0,stream>>>(kgT,vbT,gle,ST);       // overwrites kg region (dead)
    k_out<<<dim3(NCH,NH_,8),256,0,stream>>>(/*qg=*/q,ST,Apart,vbT,op);
    k_ln<<<dim3(TLEN,NH_),256,0,stream>>>(op,oln);
    k_gemm_ys<<<dim3(8,16,NH_),256,0,stream>>>(oln,w_encv,xs,/*xy=*/q);  // last read of xs
    k_gemm<true><<<dim3(8,2,16),256,0,stream>>>(q,HN,w_dec,HN,ypart,DDIM,512); // writes over xs
    k_post<<<TLEN,256,0,stream>>>(ypart,xin,x0,rlam,xlam,backout,li,xin_bf,xf);
  }
  k_gemm_lm<<<dim3(2,393),256,0,stream>>>(xf, lm_w, out);
}

// Round 13
// 646.822 us; speedup vs baseline: 1.3680x; 1.0856x over previous
//
#include <hip/hip_runtime.h>
#include <math.h>

#define TLEN 1024
#define DDIM 256
#define NH_  4
#define NDIM 2048
#define HN   8192
#define NCH  16
#define CHK  64
#define VP_  50304
#define SCALE_Q 0.022097086912079608f  // 2048^-0.5

typedef unsigned short u16;
typedef __attribute__((ext_vector_type(8))) short short8;
typedef __attribute__((ext_vector_type(4))) float f32x4;

#define MFMA16(a,b,c) __builtin_amdgcn_mfma_f32_16x16x32_bf16((a),(b),(c),0,0,0)

__device__ __forceinline__ float bf2f(u16 u){ return __uint_as_float(((unsigned)u)<<16); }
__device__ __forceinline__ u16 f2bf(float f){
  unsigned x = __float_as_uint(f);
  return (u16)((x + 0x7fffu + ((x>>16)&1u)) >> 16);
}
__device__ __forceinline__ float wave_sum(float v){
  #pragma unroll
  for(int o=1;o<64;o<<=1) v += __shfl_xor(v,o,64);
  return v;
}
__device__ __forceinline__ float block_sum(float v, float* tmp){
  v = wave_sum(v);
  __syncthreads();
  if((threadIdx.x&63)==0) tmp[threadIdx.x>>6]=v;
  __syncthreads();
  return tmp[0]+tmp[1]+tmp[2]+tmp[3];
}

// ---- async global->LDS staging (linear LDS layout, 16B/lane) ----
__device__ __forceinline__ void gload16(const u16* g, u16* l){
  __builtin_amdgcn_global_load_lds((const __attribute__((address_space(1))) unsigned int*)g,
                                   (__attribute__((address_space(3))) unsigned int*)l, 16, 0, 0);
}
__device__ __forceinline__ short8 frag_lin(const u16* lds, int row, int k){
  return *(const short8*)((const char*)lds + row*128 + k*2);
}
// swizzled reads (for ds_write-staged tiles)
__device__ __forceinline__ short8 frag64(const u16* lds, int row, int k){
  return *(const short8*)((const char*)lds + row*128 + ((k*2) ^ ((row&7)<<4)));
}
__device__ __forceinline__ short8 frag512(const u16* lds, int row, int k){
  return *(const short8*)((const char*)lds + row*512 + ((k*2) ^ ((row&7)<<4)));
}

// ---- merged setup: rope tables + weight cvt + embed/rmsnorm/xin0 ----
__global__ __launch_bounds__(256) void k_setup(
  const float* __restrict__ emb, const int* __restrict__ idx,
  const float* rl, const float* xl,
  const float* __restrict__ enc_w, const float* __restrict__ gate_w,
  const float* __restrict__ dec_w, const float* __restrict__ encv_w,
  u16* w_enc, u16* w_gate, u16* w_dec, u16* w_encv,
  float* cosT, float* sinT, float* x0, float* xin, u16* xin_bf){
  __shared__ float tmp[4];
  int bid = blockIdx.x, tid = threadIdx.x;
  if(bid < 1024){
    if(tid < 128){
      int t = bid, i = tid;
      float inv_freq = exp2f(-18.0f * (float)(2*i) * (1.0f/256.0f));
      float fr = (float)t * inv_freq;
      float xsc = ((float)(2*i) + 102.4f) * (1.0f/358.4f);
      float power = ((float)t - 512.0f) * (1.0f/512.0f);
      float sc = exp2f(power * log2f(xsc));
      cosT[t*128+i] = cosf(fr)*sc;
      sinT[t*128+i] = sinf(fr)*sc;
    }
  } else if(bid < 5120){
    size_t base = (size_t)(bid-1024)*2048 + tid;
    #pragma unroll
    for(int k=0;k<8;k++){
      size_t i = base + (size_t)k*256;
      int seg = (int)(i>>21); size_t off = i & 2097151;
      const float* s; u16* dst;
      if(seg==0){ s=enc_w; dst=w_enc; } else if(seg==1){ s=gate_w; dst=w_gate; }
      else if(seg==2){ s=dec_w; dst=w_dec; } else { s=encv_w; dst=w_encv; }
      dst[off] = f2bf(s[off]);
    }
  } else {
    int t = bid - 5120, d = tid;
    float v = emb[(size_t)idx[t]*DDIM + d];
    float s = block_sum(v*v, tmp);
    float o = v * rsqrtf(s*(1.0f/DDIM) + 1e-5f);
    x0[t*DDIM+d] = o;
    float xi = rl[0]*o + xl[0]*o;
    xin[t*DDIM+d] = xi; xin_bf[t*DDIM+d] = f2bf(xi);
  }
}

// ---- generic bf16 GEMM: C = A @ B^T fp32; SPLITK -> per-z partial buffer ----
template<bool SPLITK>
__global__ __launch_bounds__(256) void k_gemm(
  const u16* __restrict__ A, int lda, const u16* __restrict__ B, int ldb,
  float* __restrict__ C, int ldc, int kchunk)
{
  __shared__ __align__(16) u16 sA[128*64];
  __shared__ __align__(16) u16 sB[128*64];
  const int m0 = blockIdx.x*128, n0 = blockIdx.y*128;
  const int k0 = blockIdx.z*kchunk;
  const int tid = threadIdx.x, lane = tid&63, wv = tid>>6;
  const int wr = (wv>>1)*64, wc = (wv&1)*64;
  f32x4 acc[4][4];
  #pragma unroll
  for(int i=0;i<4;i++)
    #pragma unroll
    for(int j=0;j<4;j++) acc[i][j] = (f32x4){0.f,0.f,0.f,0.f};
  for(int kb=0; kb<kchunk; kb+=64){
    __syncthreads();
    #pragma unroll
    for(int p=0;p<4;p++){
      int r = p*32 + (tid>>3), cb = tid&7;
      int off = r*64 + cb*8;
      gload16(A + (size_t)(m0+r)*lda + k0+kb + cb*8, sA + off);
      gload16(B + (size_t)(n0+r)*ldb + k0+kb + cb*8, sB + off);
    }
    __syncthreads();
    #pragma unroll
    for(int ks=0;ks<2;ks++){
      short8 af[4], bfr[4];
      int kk = ks*32 + 8*(lane>>4);
      #pragma unroll
      for(int i=0;i<4;i++){
        af[i]  = frag_lin(sA, wr + i*16 + (lane&15), kk);
        bfr[i] = frag_lin(sB, wc + i*16 + (lane&15), kk);
      }
      #pragma unroll
      for(int i=0;i<4;i++)
        #pragma unroll
        for(int j=0;j<4;j++)
          acc[i][j] = MFMA16(af[i], bfr[j], acc[i][j]);
    }
  }
  size_t poff = SPLITK ? (size_t)blockIdx.z * (size_t)gridDim.x * 128 * ldc : 0;
  const int rb = 4*(lane>>4), cb2 = lane&15;
  #pragma unroll
  for(int i=0;i<4;i++)
    #pragma unroll
    for(int j=0;j<4;j++){
      int col = n0 + wc + j*16 + cb2;
      #pragma unroll
      for(int r=0;r<4;r++){
        int row = m0 + wr + i*16 + rb + r;
        C[poff + (size_t)row*ldc + col] = acc[i][j][r];
      }
    }
}

// ---- lm GEMM: B panel fp32 -> bf16 LDS-resident once; loop 4 M-tiles ----
__global__ __launch_bounds__(256) void k_gemm_lm(
  const u16* __restrict__ A, const float* __restrict__ Bf, float* __restrict__ C)
{
  __shared__ __align__(16) u16 sB[128*256];   // 64 KB, 512B rows, swizzled
  __shared__ __align__(16) u16 sA[128*64];    // 16 KB
  const int n0 = blockIdx.y*128, mbase = blockIdx.x*4;
  const int tid = threadIdx.x, lane = tid&63, wv = tid>>6;
  const int wr = (wv>>1)*64, wc = (wv&1)*64;
  {
    int n = tid>>1, half = tid&1;
    const float* bp = Bf + (size_t)(n0+n)*DDIM + half*128;
    #pragma unroll
    for(int s=0;s<16;s++){
      f32x4 v0 = *(const f32x4*)(bp + s*8);
      f32x4 v1 = *(const f32x4*)(bp + s*8 + 4);
      short8 w;
      #pragma unroll
      for(int e=0;e<4;e++){ w[e]=(short)f2bf(v0[e]); w[e+4]=(short)f2bf(v1[e]); }
      int k0 = half*128 + s*8;
      *(short8*)((char*)sB + n*512 + ((k0*2) ^ ((n&7)<<4))) = w;
    }
  }
  for(int mi=0; mi<4; mi++){
    int m0 = (mbase+mi)*128;
    f32x4 acc[4][4];
    #pragma unroll
    for(int i=0;i<4;i++)
      #pragma unroll
      for(int j=0;j<4;j++) acc[i][j] = (f32x4){0.f,0.f,0.f,0.f};
    for(int kb=0; kb<4; kb++){
      __syncthreads();
      #pragma unroll
      for(int p=0;p<4;p++){
        int r = p*32 + (tid>>3), cb = tid&7;
        gload16(A + (size_t)(m0+r)*DDIM + kb*64 + cb*8, sA + r*64 + cb*8);
      }
      __syncthreads();
      #pragma unroll
      for(int ks=0;ks<2;ks++){
        short8 af[4], bfr[4];
        int kk = ks*32 + 8*(lane>>4);
        #pragma unroll
        for(int i=0;i<4;i++){
          af[i]  = frag_lin(sA, wr + i*16 + (lane&15), kk);
          bfr[i] = frag512(sB, wc + i*16 + (lane&15), kb*64 + kk);
        }
        #pragma unroll
        for(int i=0;i<4;i++)
          #pragma unroll
          for(int j=0;j<4;j++)
            acc[i][j] = MFMA16(af[i], bfr[j], acc[i][j]);
      }
    }
    const int rb = 4*(lane>>4), cb2 = lane&15;
    #pragma unroll
    for(int i=0;i<4;i++)
      #pragma unroll
      for(int j=0;j<4;j++){
        int col = n0 + wc + j*16 + cb2;
        #pragma unroll
        for(int r=0;r<4;r++){
          int row = m0 + wr + i*16 + rb + r;
          C[(size_t)row*VP_ + col] = acc[i][j][r];
        }
      }
  }
}

// ---- fused enc+gate GEMM (128x128 tile, high TLP; B is L2-resident) ----
__global__ __launch_bounds__(256) void k_gemm_eg(
  const u16* __restrict__ xin_bf, const u16* __restrict__ w_enc, const u16* __restrict__ w_gate,
  u16* __restrict__ xs, u16* __restrict__ gate)
{
  __shared__ __align__(16) u16 sA[128*64];
  __shared__ __align__(16) u16 sB[128*64];
  const int yy = blockIdx.y;
  const bool isg = yy >= 64;
  const u16* B = isg ? w_gate : w_enc;
  u16* C = isg ? gate : xs;
  const float mul = isg ? (1.0f/1024.0f) : 1.0f;
  const int m0 = blockIdx.x*128, n0 = (yy&63)*128;
  const int tid = threadIdx.x, lane = tid&63, wv = tid>>6;
  const int wr = (wv>>1)*64, wc = (wv&1)*64;
  f32x4 acc[4][4];
  #pragma unroll
  for(int i=0;i<4;i++)
    #pragma unroll
    for(int j=0;j<4;j++) acc[i][j] = (f32x4){0.f,0.f,0.f,0.f};
  for(int kb=0; kb<DDIM; kb+=64){
    __syncthreads();
    #pragma unroll
    for(int p=0;p<4;p++){
      int r = p*32 + (tid>>3), cb = tid&7;
      int off = r*64 + cb*8;
      gload16(xin_bf + (size_t)(m0+r)*DDIM + kb + cb*8, sA + off);
      gload16(B + (size_t)(n0+r)*DDIM + kb + cb*8, sB + off);
    }
    __syncthreads();
    #pragma unroll
    for(int ks=0;ks<2;ks++){
      short8 af[4], bfr[4];
      int kk = ks*32 + 8*(lane>>4);
      #pragma unroll
      for(int i=0;i<4;i++){
        af[i]  = frag_lin(sA, wr + i*16 + (lane&15), kk);
        bfr[i] = frag_lin(sB, wc + i*16 + (lane&15), kk);
      }
      #pragma unroll
      for(int i=0;i<4;i++)
        #pragma unroll
        for(int j=0;j<4;j++)
          acc[i][j] = MFMA16(af[i], bfr[j], acc[i][j]);
    }
  }
  const int rb = 4*(lane>>4), cb2 = lane&15;
  #pragma unroll
  for(int i=0;i<4;i++)
    #pragma unroll
    for(int j=0;j<4;j++){
      int col = n0 + wc + j*16 + cb2;
      #pragma unroll
      for(int r=0;r<4;r++){
        int row = m0 + wr + i*16 + rb + r;
        float v = acc[i][j][r];
        float a = v>0.f ? v*v*mul : 0.f;
        C[(size_t)row*HN + col] = f2bf(a);
      }
    }
}

// ---- ys GEMM, batched over heads ----
__global__ __launch_bounds__(256) void k_gemm_ys(
  const u16* __restrict__ olnp, const u16* __restrict__ wvp,
  const u16* __restrict__ xs, u16* __restrict__ xy)
{
  __shared__ __align__(16) u16 sA[128*64];
  __shared__ __align__(16) u16 sB[128*64];
  const int m0 = blockIdx.x*128, n0 = blockIdx.y*128, h = blockIdx.z;
  const u16* A = olnp + (size_t)h*TLEN*DDIM;
  const u16* B = wvp  + (size_t)h*NDIM*DDIM;
  const int tid = threadIdx.x, lane = tid&63, wv = tid>>6;
  const int wr = (wv>>1)*64, wc = (wv&1)*64;
  f32x4 acc[4][4];
  #pragma unroll
  for(int i=0;i<4;i++)
    #pragma unroll
    for(int j=0;j<4;j++) acc[i][j] = (f32x4){0.f,0.f,0.f,0.f};
  for(int kb=0; kb<DDIM; kb+=64){
    __syncthreads();
    #pragma unroll
    for(int p=0;p<4;p++){
      int r = p*32 + (tid>>3), cb = tid&7;
      int off = r*64 + cb*8;
      gload16(A + (size_t)(m0+r)*DDIM + kb + cb*8, sA + off);
      gload16(B + (size_t)(n0+r)*DDIM + kb + cb*8, sB + off);
    }
    __syncthreads();
    #pragma unroll
    for(int ks=0;ks<2;ks++){
      short8 af[4], bfr[4];
      int kk = ks*32 + 8*(lane>>4);
      #pragma unroll
      for(int i=0;i<4;i++){
        af[i]  = frag_lin(sA, wr + i*16 + (lane&15), kk);
        bfr[i] = frag_lin(sB, wc + i*16 + (lane&15), kk);
      }
      #pragma unroll
      for(int i=0;i<4;i++)
        #pragma unroll
        for(int j=0;j<4;j++)
          acc[i][j] = MFMA16(af[i], bfr[j], acc[i][j]);
    }
  }
  const int rb = 4*(lane>>4), cb2 = lane&15;
  #pragma unroll
  for(int i=0;i<4;i++)
    #pragma unroll
    for(int j=0;j<4;j++){
      int col = h*NDIM + n0 + wc + j*16 + cb2;
      #pragma unroll
      for(int r=0;r<4;r++){
        int row = m0 + wr + i*16 + rb + r;
        float v = acc[i][j][r];
        float a = v>0.f ? v*v : 0.f;
        a *= bf2f(xs[(size_t)row*HN + col]);
        xy[(size_t)row*HN + col] = f2bf(a);
      }
    }
}

// ---- phase A (rope + vbT fused): qg -> q, kg in-place over gate, gle ----
__global__ __launch_bounds__(256) void k_phase_a(const u16* __restrict__ xs, u16* __restrict__ gate,
                          const float* __restrict__ cosT, const float* __restrict__ sinT,
                          u16* __restrict__ qg, float* __restrict__ gle,
                          const u16* __restrict__ xin_bf, u16* __restrict__ vbT){
  __shared__ u16 s[64*DDIM];
  int c = blockIdx.y;
  if(blockIdx.x == 32){
    int tid = threadIdx.x;
    #pragma unroll
    for(int p=0;p<8;p++){
      int idx = p*256+tid; int t = idx>>5, cb = idx&31;
      *(short8*)(s + t*DDIM + cb*8) = *(const short8*)(xin_bf + ((size_t)c*CHK + t)*DDIM + cb*8);
    }
    __syncthreads();
    int d = tid;
    u16 col[64];
    #pragma unroll
    for(int t=0;t<64;t++) col[t] = s[t*DDIM + d];
    u16* dst = vbT + ((size_t)c*DDIM + d)*CHK;
    #pragma unroll
    for(int p=0;p<8;p++){
      short8 v;
      #pragma unroll
      for(int e=0;e<8;e++) v[e] = (short)col[p*8+e];
      *(short8*)(dst + p*8) = v;
    }
    return;
  }
  int j = blockIdx.x*256 + threadIdx.x;
  int cc = j & 255;
  int ci = cc & 127;
  bool hi_ = cc >= 128;
  int poff = hi_ ? -128 : 128;
  size_t base = (size_t)c*CHK*HN + j;
  float gsum = 0.f;
  #pragma unroll
  for(int t=0;t<CHK;t++) gsum -= bf2f(gate[base + (size_t)t*HN]);
  float egsum = expf(gsum);
  float gc = 0.f;
  #pragma unroll
  for(int t=0;t<CHK;t++){
    size_t ix = base + (size_t)t*HN;
    gc -= bf2f(gate[ix]);
    int tt = c*CHK + t;
    float own = bf2f(xs[ix]), oth = bf2f(xs[ix + poff]);
    float cs = cosT[tt*128+ci], sn = sinT[tt*128+ci];
    float qv = hi_ ? (own*cs + oth*sn) : (own*cs - oth*sn);
    float e1 = expf(gc);
    qg[ix] = f2bf(qv * e1 * SCALE_Q);
    gate[ix] = f2bf(qv / e1);       // kg in-place (each elem read before overwritten)
  }
  gle[(size_t)c*HN + j] = egsum;
}

// ---- merged QK^T partials + state chain (both READ kg; ST is a disjoint buffer) ----
// blocks [0,256): Apart[kz][c][h] = qg-slice @ kg-slice^T (compute-bound)
// blocks [256,1280): boundary-state serial chains (latency-bound; kg transposed in LDS)
__global__ __launch_bounds__(256) void k_qk_state(
  const u16* __restrict__ qg, const u16* __restrict__ kg, float* __restrict__ Apart,
  const u16* __restrict__ vbT, const float* __restrict__ gle, u16* __restrict__ ST){
  __shared__ __align__(16) u16 smem[16384];   // 32 KB union
  int bid = blockIdx.x;
  int tid = threadIdx.x, lane = tid&63, wv = tid>>6;
  if(bid < 256){
    int c = bid&15, h = (bid>>4)&3, kz = bid>>6;
    const u16* qb = qg + (size_t)c*CHK*HN + h*NDIM + kz*512;
    const u16* kb = kg + (size_t)c*CHK*HN + h*NDIM + kz*512;
    f32x4 acc[4];
    #pragma unroll
    for(int j=0;j<4;j++) acc[j] = (f32x4){0.f,0.f,0.f,0.f};
    #pragma unroll
    for(int p=0;p<2;p++){
      int r = p*32 + (tid>>3), cb = tid&7;
      int off = r*64 + cb*8;
      gload16(qb + (size_t)r*HN + cb*8, smem + off);            // sQ buf0 @ u16 0
      gload16(kb + (size_t)r*HN + cb*8, smem + 8192 + off);     // sK buf0 @ u16 8192
    }
    __syncthreads();
    for(int kt=0; kt<8; kt++){
      int curo = (kt&1)*4096, nxto = ((kt+1)&1)*4096;
      if(kt<7){
        #pragma unroll
        for(int p=0;p<2;p++){
          int r = p*32 + (tid>>3), cb = tid&7;
          int off = r*64 + cb*8;
          gload16(qb + (kt+1)*64 + (size_t)r*HN + cb*8, smem + nxto + off);
          gload16(kb + (kt+1)*64 + (size_t)r*HN + cb*8, smem + 8192 + nxto + off);
        }
      }
      #pragma unroll
      for(int kh=0;kh<2;kh++){
        int kk = kh*32 + 8*(lane>>4);
        short8 af = frag_lin(smem + curo, wv*16 + (lane&15), kk);
        #pragma unroll
        for(int j=0;j<4;j++){
          short8 b = frag_lin(smem + 8192 + curo, j*16 + (lane&15), kk);
          acc[j] = MFMA16(af, b, acc[j]);
        }
      }
      __syncthreads();
    }
    int rb = 4*(lane>>4), cl = lane&15;
    float* ab = Apart + (size_t)kz*(NCH*NH_*4096) + ((size_t)c*NH_+h)*4096;
    #pragma unroll
    for(int j=0;j<4;j++)
      #pragma unroll
      for(int r=0;r<4;r++){
        int t = wv*16 + rb + r, s = j*16 + cl;
        ab[t*64 + s] = acc[j][r];
      }
  } else {
    // state chain: idx: nb=idx&63 (32 n), db=(idx>>6)&3 (64 d), h=idx>>8
    // LDS bytes: sK[2] @ [0,4096)/[4096,8192); sV[2] @ [8192,16384)/[16384,24576); sD @ [24576,28672)
    int idx = bid - 256;
    int nb = idx&63, db = (idx>>6)&3, h = idx>>8;
    int ng = nb*32;
    int r8a = tid>>3, cb = tid&7;
    int tr = tid>>2, tseg = tid&3;   // kg row t (0..63), n-seg (0..3)
    f32x4 S[2];
    S[0] = (f32x4){0.f,0.f,0.f,0.f}; S[1] = (f32x4){0.f,0.f,0.f,0.f};
    short8 kreg = *(const short8*)(kg + (size_t)tr*HN + h*NDIM + ng + tseg*8);
    #pragma unroll
    for(int p=0;p<2;p++){
      int r = p*32 + r8a;
      gload16(vbT + ((size_t)0*DDIM + db*64 + r)*CHK + cb*8, smem + 4096 + r*64 + cb*8);
    }
    int cur = 0;
    for(int c=0;c<15;c++){
      // scatter kreg -> sK[cur] (transposed, swizzled): sK[n][t]
      #pragma unroll
      for(int e=0;e<8;e++){
        int n = tseg*8 + e;
        *(u16*)((char*)smem + cur*4096 + n*128 + ((tr*2) ^ ((n&7)<<4))) = (u16)kreg[e];
      }
      __syncthreads();    // sK scatter + sV gloads visible
      if(c<14){
        kreg = *(const short8*)(kg + (size_t)((c+1)*CHK + tr)*HN + h*NDIM + ng + tseg*8);
        int nxt = cur^1;
        #pragma unroll
        for(int p=0;p<2;p++){
          int r = p*32 + r8a;
          gload16(vbT + ((size_t)(c+1)*DDIM + db*64 + r)*CHK + cb*8, smem + 4096 + nxt*4096 + r*64 + cb*8);
        }
      }
      #pragma unroll
      for(int kh=0;kh<2;kh++){
        int kk = kh*32 + 8*(lane>>4);
        short8 af = frag_lin(smem + 4096 + cur*4096, wv*16 + (lane&15), kk);
        #pragma unroll
        for(int fn=0;fn<2;fn++){
          short8 b = frag64(smem + cur*2048, fn*16 + (lane&15), kk);
          S[fn] = MFMA16(af, b, S[fn]);
        }
      }
      #pragma unroll
      for(int fn=0;fn<2;fn++){
        float gv = gle[(size_t)c*HN + h*NDIM + ng + fn*16 + (lane&15)];
        S[fn][0]*=gv; S[fn][1]*=gv; S[fn][2]*=gv; S[fn][3]*=gv;
      }
      #pragma unroll
      for(int fn=0;fn<2;fn++)
        #pragma unroll
        for(int r=0;r<4;r++){
          int d = wv*16 + 4*(lane>>4) + r, n = fn*16 + (lane&15);
          *(u16*)((char*)(smem + 12288) + d*64 + ((n*2) ^ (((d>>2)&3)<<4))) = f2bf(S[fn][r]);
        }
      __syncthreads();    // sD visible; drains next-tile sV gloads too
      {
        int dl = tid>>2, seg = tid&3;
        short8 v = *(const short8*)((const char*)(smem + 12288) + dl*64 + ((seg*16) ^ (((dl>>2)&3)<<4)));
        *(short8*)(ST + (((size_t)c*NH_ + h)*DDIM + db*64 + dl)*NDIM + ng + seg*8) = v;
      }
      cur ^= 1;
    }
  }
}

// ---- fused output, n-split ×2 ----
__global__ __launch_bounds__(256) void k_out(const u16* __restrict__ qg, const u16* __restrict__ ST,
                                             const float* __restrict__ Apart, const u16* __restrict__ vbT,
                                             float* __restrict__ op){
  int c = blockIdx.x, h = blockIdx.y, zz = blockIdx.z;
  int db = zz>>1, nz = zz&1;
  int tid = threadIdx.x, lane = tid&63, wv = tid>>6;
  __shared__ __align__(16) u16 sQ[2][64*64], sS[2][64*64];
  __shared__ __align__(16) u16 sAm[64*64], sV[64*64];
  const u16* stb = (c>0) ? ST + ((size_t)(c-1)*NH_ + h)*DDIM*(size_t)NDIM + (size_t)db*64*NDIM : ST;
  const u16* qb  = qg + (size_t)c*CHK*HN + h*NDIM;
  const int ktA = nz ? 15 : 0, ktB = nz ? 32 : 15;
  int r8a = tid>>3, cb = tid&7;
  f32x4 acc[4];
  #pragma unroll
  for(int j=0;j<4;j++) acc[j] = (f32x4){0.f,0.f,0.f,0.f};
  if(c>0){
    #pragma unroll
    for(int p=0;p<2;p++){
      int r = p*32 + r8a;
      gload16(qb + ktA*64 + (size_t)r*HN + cb*8, sQ[0] + r*64 + cb*8);
      gload16(stb + (size_t)r*NDIM + ktA*64 + cb*8, sS[0] + r*64 + cb*8);
    }
  }
  if(nz==0){
    size_t abase = ((size_t)c*NH_ + h)*4096;
    #pragma unroll
    for(int e=0;e<16;e++){
      int idx = e*256 + tid;
      int t = idx>>6, s = idx&63;
      float sum = Apart[abase + idx]
                + Apart[(size_t)(NCH*NH_*4096)   + abase + idx]
                + Apart[(size_t)(NCH*NH_*4096)*2 + abase + idx]
                + Apart[(size_t)(NCH*NH_*4096)*3 + abase + idx];
      *(u16*)((char*)sAm + t*128 + ((s*2)^((t&7)<<4))) = f2bf((s<=t)? sum : 0.f);
    }
    #pragma unroll
    for(int p=0;p<2;p++){
      int r = p*32 + r8a;
      gload16(vbT + ((size_t)c*DDIM + db*64 + r)*CHK + cb*8, sV + r*64 + cb*8);
    }
  }
  __syncthreads();
  if(nz==0){
    #pragma unroll
    for(int kh=0;kh<2;kh++){
      int kk = kh*32 + 8*(lane>>4);
      short8 af = frag64(sAm, wv*16 + (lane&15), kk);
      #pragma unroll
      for(int j=0;j<4;j++){
        short8 b = frag_lin(sV, j*16 + (lane&15), kk);
        acc[j] = MFMA16(af, b, acc[j]);
      }
    }
  }
  if(c>0){
    int cur = 0;
    for(int kt=ktA; kt<ktB; kt++){
      if(kt+1<ktB){
        #pragma unroll
        for(int p=0;p<2;p++){
          int r = p*32 + r8a;
          gload16(qb + (kt+1)*64 + (size_t)r*HN + cb*8, sQ[cur^1] + r*64 + cb*8);
          gload16(stb + (size_t)r*NDIM + (kt+1)*64 + cb*8, sS[cur^1] + r*64 + cb*8);
        }
      }
      #pragma unroll
      for(int kh=0;kh<2;kh++){
        int kk = kh*32 + 8*(lane>>4);
        short8 af = frag_lin(sQ[cur], wv*16 + (lane&15), kk);
        #pragma unroll
        for(int j=0;j<4;j++){
          short8 b = frag_lin(sS[cur], j*16 + (lane&15), kk);
          acc[j] = MFMA16(af, b, acc[j]);
        }
      }
      __syncthreads();
      cur ^= 1;
    }
  }
  int rb = 4*(lane>>4), cl = lane&15;
  #pragma unroll
  for(int j=0;j<4;j++){
    int d = db*64 + j*16 + cl;
    #pragma unroll
    for(int r=0;r<4;r++){
      int t = c*CHK + wv*16 + rb + r;
      op[((size_t)(nz*NH_ + h)*TLEN + t)*DDIM + d] = acc[j][r];
    }
  }
}

// ---- layernorm over d of op0+op1 -> oln bf16 ----
__global__ __launch_bounds__(256) void k_ln(const float* __restrict__ op, u16* __restrict__ oln){
  __shared__ float tmp[4];
  int t = blockIdx.x, h = blockIdx.y, d = threadIdx.x;
  size_t ix = ((size_t)h*TLEN + t)*DDIM + d;
  float v = op[ix] + op[(size_t)NH_*TLEN*DDIM + ix];
  float s1 = block_sum(v, tmp);
  float m = s1*(1.0f/DDIM);
  float cv = v - m;
  float s2 = block_sum(cv*cv, tmp);
  oln[ix] = f2bf(cv * rsqrtf(s2*(1.0f/DDIM) + 1e-5f));
}

// ---- dec epilogue ----
__global__ __launch_bounds__(256) void k_post(const float* __restrict__ ypart, float* __restrict__ xin,
                                              const float* __restrict__ x0,
                                              const float* rl, const float* xl, const float* bl,
                                              int li, u16* __restrict__ xin_bf, u16* __restrict__ xf){
  __shared__ float tmp[4];
  int t = blockIdx.x, d = threadIdx.x;
  float v = 0.f;
  #pragma unroll
  for(int z=0;z<16;z++) v += ypart[(size_t)z*TLEN*DDIM + t*DDIM + d];
  float s1 = block_sum(v, tmp);
  float m = s1*(1.0f/DDIM);
  float cvt = v - m;
  float s2 = block_sum(cvt*cvt, tmp);
  float y = cvt * rsqrtf(s2*(1.0f/DDIM) + 1e-5f);
  float xn = y + xin[t*DDIM+d];
  float s3 = block_sum(xn*xn, tmp);
  float xv = xn * rsqrtf(s3*(1.0f/DDIM) + 1e-5f);
  if(li<3){
    float xi = rl[li+1]*xv + xl[li+1]*x0[t*DDIM+d];
    xin[t*DDIM+d] = xi; xin_bf[t*DDIM+d] = f2bf(xi);
  } else {
    float fv = xv - bl[0]*x0[t*DDIM+d];
    float s4 = block_sum(fv*fv, tmp);
    xf[t*DDIM+d] = f2bf(fv * rsqrtf(s4*(1.0f/DDIM) + 1e-5f));
  }
}

extern "C" void kernel_launch(void* const* d_in, const int* in_sizes, int n_in,
                              void* d_out, int out_size, void* d_ws, size_t ws_size,
                              hipStream_t stream){
  (void)in_sizes; (void)n_in; (void)out_size; (void)ws_size;
  const float* embed_w = (const float*)d_in[0];
  const float* lm_w    = (const float*)d_in[1];
  const float* enc_w   = (const float*)d_in[2];
  const float* gate_w  = (const float*)d_in[3];
  const float* dec_w   = (const float*)d_in[4];
  const float* encv_w  = (const float*)d_in[5];
  const float* backout = (const float*)d_in[6];
  const float* rlam    = (const float*)d_in[7];
  const float* xlam    = (const float*)d_in[8];
  const int*   idx     = (const int*)d_in[9];
  float* out = (float*)d_out;

  // layout total ≈150 MB — same footprint as the passing round-9/11 layouts.
  char* p = (char*)d_ws;
  auto alloc = [&](size_t b)->char*{ char* r=p; p += (b+255)&~(size_t)255; return r; };
  float* cosT = (float*)alloc((size_t)TLEN*128*4);
  float* sinT = (float*)alloc((size_t)TLEN*128*4);
  float* x0   = (float*)alloc((size_t)TLEN*DDIM*4);
  float* xin  = (float*)alloc((size_t)TLEN*DDIM*4);
  u16* xin_bf = (u16*)alloc((size_t)TLEN*DDIM*2);
  u16* xs     = (u16*)alloc((size_t)TLEN*HN*2);        // dec partials alias this
  u16* q      = (u16*)alloc((size_t)TLEN*HN*2);        // qg, later xy
  u16* gate   = (u16*)alloc((size_t)TLEN*HN*2);        // gate -> kg in-place; dead after k_qk_state
  u16* ST     = (u16*)alloc((size_t)15*NH_*DDIM*NDIM*2); // 62.9 MB dedicated (disjoint from kg!)
  float* ypart= (float*)xs; // live dec..post (xs dead)
  float* gle  = (float*)alloc((size_t)NCH*HN*4);
  u16* vbT    = (u16*)alloc((size_t)NCH*DDIM*CHK*2);
  float* Apart= (float*)alloc((size_t)4*NCH*NH_*CHK*CHK*4);
  float* op   = (float*)alloc((size_t)2*NH_*TLEN*DDIM*4);   // 8.39 MB
  u16* oln    = (u16*)alloc((size_t)NH_*TLEN*DDIM*2);
  u16* xf     = (u16*)alloc((size_t)TLEN*DDIM*2);
  u16* w_enc  = (u16*)alloc((size_t)HN*DDIM*2);
  u16* w_gate = (u16*)alloc((size_t)HN*DDIM*2);
  u16* w_dec  = (u16*)alloc((size_t)DDIM*HN*2);
  u16* w_encv = (u16*)alloc((size_t)NH_*NDIM*DDIM*2);

  k_setup<<<6144,256,0,stream>>>(embed_w, idx, rlam, xlam,
                                 enc_w, gate_w, dec_w, encv_w,
                                 w_enc, w_gate, w_dec, w_encv,
                                 cosT, sinT, x0, xin, xin_bf);

  for(int li=0; li<4; li++){
    k_gemm_eg<<<dim3(8,128),256,0,stream>>>(xin_bf,w_enc,w_gate,xs,gate);
    k_phase_a<<<dim3(33,NCH),256,0,stream>>>(xs,gate,cosT,sinT,/*qg=*/q,gle,xin_bf,vbT);
    k_qk_state<<<1280,256,0,stream>>>(/*qg=*/q,/*kg=*/gate,Apart,vbT,gle,ST);  // qk ∥ state
    k_out<<<dim3(NCH,NH_,8),256,0,stream>>>(/*qg=*/q,ST,Apart,vbT,op);
    k_ln<<<dim3(TLEN,NH_),256,0,stream>>>(op,oln);
    k_gemm_ys<<<dim3(8,16,NH_),256,0,stream>>>(oln,w_encv,xs,/*xy=*/q);   // last read of xs
    k_gemm<true><<<dim3(8,2,16),256,0,stream>>>(q,HN,w_dec,HN,ypart,DDIM,512); // writes over xs
    k_post<<<TLEN,256,0,stream>>>(ypart,xin,x0,rlam,xlam,backout,li,xin_bf,xf);
  }
  k_gemm_lm<<<dim3(2,393),256,0,stream>>>(xf, lm_w, out);
}

// Round 14
// 637.260 us; speedup vs baseline: 1.3885x; 1.0150x over previous
//
#include <hip/hip_runtime.h>
#include <math.h>

#define TLEN 1024
#define DDIM 256
#define NH_  4
#define NDIM 2048
#define HN   8192
#define NCH  16
#define CHK  64
#define VP_  50304
#define SCALE_Q 0.022097086912079608f  // 2048^-0.5

typedef unsigned short u16;
typedef __attribute__((ext_vector_type(8))) short short8;
typedef __attribute__((ext_vector_type(4))) float f32x4;

#define MFMA16(a,b,c) __builtin_amdgcn_mfma_f32_16x16x32_bf16((a),(b),(c),0,0,0)

__device__ __forceinline__ float bf2f(u16 u){ return __uint_as_float(((unsigned)u)<<16); }
__device__ __forceinline__ u16 f2bf(float f){
  unsigned x = __float_as_uint(f);
  return (u16)((x + 0x7fffu + ((x>>16)&1u)) >> 16);
}
__device__ __forceinline__ float wave_sum(float v){
  #pragma unroll
  for(int o=1;o<64;o<<=1) v += __shfl_xor(v,o,64);
  return v;
}
__device__ __forceinline__ float block_sum(float v, float* tmp){
  v = wave_sum(v);
  __syncthreads();
  if((threadIdx.x&63)==0) tmp[threadIdx.x>>6]=v;
  __syncthreads();
  return tmp[0]+tmp[1]+tmp[2]+tmp[3];
}

// ---- async global->LDS staging (linear LDS layout, 16B/lane) ----
__device__ __forceinline__ void gload16(const u16* g, u16* l){
  __builtin_amdgcn_global_load_lds((const __attribute__((address_space(1))) unsigned int*)g,
                                   (__attribute__((address_space(3))) unsigned int*)l, 16, 0, 0);
}
__device__ __forceinline__ short8 frag_lin(const u16* lds, int row, int k){
  return *(const short8*)((const char*)lds + row*128 + k*2);
}
// swizzled reads (for ds_write-staged tiles)
__device__ __forceinline__ short8 frag64(const u16* lds, int row, int k){
  return *(const short8*)((const char*)lds + row*128 + ((k*2) ^ ((row&7)<<4)));
}
__device__ __forceinline__ short8 frag512(const u16* lds, int row, int k){
  return *(const short8*)((const char*)lds + row*512 + ((k*2) ^ ((row&7)<<4)));
}

// ---- merged setup: rope tables + weight cvt + embed/rmsnorm/xin0 ----
__global__ __launch_bounds__(256) void k_setup(
  const float* __restrict__ emb, const int* __restrict__ idx,
  const float* rl, const float* xl,
  const float* __restrict__ enc_w, const float* __restrict__ gate_w,
  const float* __restrict__ dec_w, const float* __restrict__ encv_w,
  u16* w_enc, u16* w_gate, u16* w_dec, u16* w_encv,
  float* cosT, float* sinT, float* x0, float* xin, u16* xin_bf){
  __shared__ float tmp[4];
  int bid = blockIdx.x, tid = threadIdx.x;
  if(bid < 1024){
    if(tid < 128){
      int t = bid, i = tid;
      float inv_freq = exp2f(-18.0f * (float)(2*i) * (1.0f/256.0f));
      float fr = (float)t * inv_freq;
      float xsc = ((float)(2*i) + 102.4f) * (1.0f/358.4f);
      float power = ((float)t - 512.0f) * (1.0f/512.0f);
      float sc = exp2f(power * log2f(xsc));
      cosT[t*128+i] = cosf(fr)*sc;
      sinT[t*128+i] = sinf(fr)*sc;
    }
  } else if(bid < 5120){
    size_t base = (size_t)(bid-1024)*2048 + tid;
    #pragma unroll
    for(int k=0;k<8;k++){
      size_t i = base + (size_t)k*256;
      int seg = (int)(i>>21); size_t off = i & 2097151;
      const float* s; u16* dst;
      if(seg==0){ s=enc_w; dst=w_enc; } else if(seg==1){ s=gate_w; dst=w_gate; }
      else if(seg==2){ s=dec_w; dst=w_dec; } else { s=encv_w; dst=w_encv; }
      dst[off] = f2bf(s[off]);
    }
  } else {
    int t = bid - 5120, d = tid;
    float v = emb[(size_t)idx[t]*DDIM + d];
    float s = block_sum(v*v, tmp);
    float o = v * rsqrtf(s*(1.0f/DDIM) + 1e-5f);
    x0[t*DDIM+d] = o;
    float xi = rl[0]*o + xl[0]*o;
    xin[t*DDIM+d] = xi; xin_bf[t*DDIM+d] = f2bf(xi);
  }
}

// ---- generic bf16 GEMM: C = A @ B^T fp32; SPLITK -> per-z partial buffer ----
template<bool SPLITK>
__global__ __launch_bounds__(256) void k_gemm(
  const u16* __restrict__ A, int lda, const u16* __restrict__ B, int ldb,
  float* __restrict__ C, int ldc, int kchunk)
{
  __shared__ __align__(16) u16 sA[128*64];
  __shared__ __align__(16) u16 sB[128*64];
  const int m0 = blockIdx.x*128, n0 = blockIdx.y*128;
  const int k0 = blockIdx.z*kchunk;
  const int tid = threadIdx.x, lane = tid&63, wv = tid>>6;
  const int wr = (wv>>1)*64, wc = (wv&1)*64;
  f32x4 acc[4][4];
  #pragma unroll
  for(int i=0;i<4;i++)
    #pragma unroll
    for(int j=0;j<4;j++) acc[i][j] = (f32x4){0.f,0.f,0.f,0.f};
  for(int kb=0; kb<kchunk; kb+=64){
    __syncthreads();
    #pragma unroll
    for(int p=0;p<4;p++){
      int r = p*32 + (tid>>3), cb = tid&7;
      int off = r*64 + cb*8;
      gload16(A + (size_t)(m0+r)*lda + k0+kb + cb*8, sA + off);
      gload16(B + (size_t)(n0+r)*ldb + k0+kb + cb*8, sB + off);
    }
    __syncthreads();
    #pragma unroll
    for(int ks=0;ks<2;ks++){
      short8 af[4], bfr[4];
      int kk = ks*32 + 8*(lane>>4);
      #pragma unroll
      for(int i=0;i<4;i++){
        af[i]  = frag_lin(sA, wr + i*16 + (lane&15), kk);
        bfr[i] = frag_lin(sB, wc + i*16 + (lane&15), kk);
      }
      #pragma unroll
      for(int i=0;i<4;i++)
        #pragma unroll
        for(int j=0;j<4;j++)
          acc[i][j] = MFMA16(af[i], bfr[j], acc[i][j]);
    }
  }
  size_t poff = SPLITK ? (size_t)blockIdx.z * (size_t)gridDim.x * 128 * ldc : 0;
  const int rb = 4*(lane>>4), cb2 = lane&15;
  #pragma unroll
  for(int i=0;i<4;i++)
    #pragma unroll
    for(int j=0;j<4;j++){
      int col = n0 + wc + j*16 + cb2;
      #pragma unroll
      for(int r=0;r<4;r++){
        int row = m0 + wr + i*16 + rb + r;
        C[poff + (size_t)row*ldc + col] = acc[i][j][r];
      }
    }
}

// ---- lm GEMM: one block per 128-col B panel; B fp32->bf16 LDS once; loop 8 M-tiles ----
__global__ __launch_bounds__(256) void k_gemm_lm(
  const u16* __restrict__ A, const float* __restrict__ Bf, float* __restrict__ C)
{
  __shared__ __align__(16) u16 sB[128*256];   // 64 KB, 512B rows, swizzled
  __shared__ __align__(16) u16 sA[128*64];    // 16 KB
  const int n0 = blockIdx.x*128;
  const int tid = threadIdx.x, lane = tid&63, wv = tid>>6;
  const int wr = (wv>>1)*64, wc = (wv&1)*64;
  {
    int n = tid>>1, half = tid&1;
    const float* bp = Bf + (size_t)(n0+n)*DDIM + half*128;
    #pragma unroll
    for(int s=0;s<16;s++){
      f32x4 v0 = *(const f32x4*)(bp + s*8);
      f32x4 v1 = *(const f32x4*)(bp + s*8 + 4);
      short8 w;
      #pragma unroll
      for(int e=0;e<4;e++){ w[e]=(short)f2bf(v0[e]); w[e+4]=(short)f2bf(v1[e]); }
      int k0 = half*128 + s*8;
      *(short8*)((char*)sB + n*512 + ((k0*2) ^ ((n&7)<<4))) = w;
    }
  }
  for(int mi=0; mi<8; mi++){
    int m0 = mi*128;
    f32x4 acc[4][4];
    #pragma unroll
    for(int i=0;i<4;i++)
      #pragma unroll
      for(int j=0;j<4;j++) acc[i][j] = (f32x4){0.f,0.f,0.f,0.f};
    for(int kb=0; kb<4; kb++){
      __syncthreads();
      #pragma unroll
      for(int p=0;p<4;p++){
        int r = p*32 + (tid>>3), cb = tid&7;
        gload16(A + (size_t)(m0+r)*DDIM + kb*64 + cb*8, sA + r*64 + cb*8);
      }
      __syncthreads();
      #pragma unroll
      for(int ks=0;ks<2;ks++){
        short8 af[4], bfr[4];
        int kk = ks*32 + 8*(lane>>4);
        #pragma unroll
        for(int i=0;i<4;i++){
          af[i]  = frag_lin(sA, wr + i*16 + (lane&15), kk);
          bfr[i] = frag512(sB, wc + i*16 + (lane&15), kb*64 + kk);
        }
        #pragma unroll
        for(int i=0;i<4;i++)
          #pragma unroll
          for(int j=0;j<4;j++)
            acc[i][j] = MFMA16(af[i], bfr[j], acc[i][j]);
      }
    }
    const int rb = 4*(lane>>4), cb2 = lane&15;
    #pragma unroll
    for(int i=0;i<4;i++)
      #pragma unroll
      for(int j=0;j<4;j++){
        int col = n0 + wc + j*16 + cb2;
        #pragma unroll
        for(int r=0;r<4;r++){
          int row = m0 + wr + i*16 + rb + r;
          C[(size_t)row*VP_ + col] = acc[i][j][r];
        }
      }
  }
}

// ---- fused enc+gate GEMM (128x128 tile, high TLP; B is L2-resident) ----
__global__ __launch_bounds__(256) void k_gemm_eg(
  const u16* __restrict__ xin_bf, const u16* __restrict__ w_enc, const u16* __restrict__ w_gate,
  u16* __restrict__ xs, u16* __restrict__ gate)
{
  __shared__ __align__(16) u16 sA[128*64];
  __shared__ __align__(16) u16 sB[128*64];
  const int yy = blockIdx.y;
  const bool isg = yy >= 64;
  const u16* B = isg ? w_gate : w_enc;
  u16* C = isg ? gate : xs;
  const float mul = isg ? (1.0f/1024.0f) : 1.0f;
  const int m0 = blockIdx.x*128, n0 = (yy&63)*128;
  const int tid = threadIdx.x, lane = tid&63, wv = tid>>6;
  const int wr = (wv>>1)*64, wc = (wv&1)*64;
  f32x4 acc[4][4];
  #pragma unroll
  for(int i=0;i<4;i++)
    #pragma unroll
    for(int j=0;j<4;j++) acc[i][j] = (f32x4){0.f,0.f,0.f,0.f};
  for(int kb=0; kb<DDIM; kb+=64){
    __syncthreads();
    #pragma unroll
    for(int p=0;p<4;p++){
      int r = p*32 + (tid>>3), cb = tid&7;
      int off = r*64 + cb*8;
      gload16(xin_bf + (size_t)(m0+r)*DDIM + kb + cb*8, sA + off);
      gload16(B + (size_t)(n0+r)*DDIM + kb + cb*8, sB + off);
    }
    __syncthreads();
    #pragma unroll
    for(int ks=0;ks<2;ks++){
      short8 af[4], bfr[4];
      int kk = ks*32 + 8*(lane>>4);
      #pragma unroll
      for(int i=0;i<4;i++){
        af[i]  = frag_lin(sA, wr + i*16 + (lane&15), kk);
        bfr[i] = frag_lin(sB, wc + i*16 + (lane&15), kk);
      }
      #pragma unroll
      for(int i=0;i<4;i++)
        #pragma unroll
        for(int j=0;j<4;j++)
          acc[i][j] = MFMA16(af[i], bfr[j], acc[i][j]);
    }
  }
  const int rb = 4*(lane>>4), cb2 = lane&15;
  #pragma unroll
  for(int i=0;i<4;i++)
    #pragma unroll
    for(int j=0;j<4;j++){
      int col = n0 + wc + j*16 + cb2;
      #pragma unroll
      for(int r=0;r<4;r++){
        int row = m0 + wr + i*16 + rb + r;
        float v = acc[i][j][r];
        float a = v>0.f ? v*v*mul : 0.f;
        C[(size_t)row*HN + col] = f2bf(a);
      }
    }
}

// ---- ys GEMM, batched over heads ----
__global__ __launch_bounds__(256) void k_gemm_ys(
  const u16* __restrict__ olnp, const u16* __restrict__ wvp,
  const u16* __restrict__ xs, u16* __restrict__ xy)
{
  __shared__ __align__(16) u16 sA[128*64];
  __shared__ __align__(16) u16 sB[128*64];
  const int m0 = blockIdx.x*128, n0 = blockIdx.y*128, h = blockIdx.z;
  const u16* A = olnp + (size_t)h*TLEN*DDIM;
  const u16* B = wvp  + (size_t)h*NDIM*DDIM;
  const int tid = threadIdx.x, lane = tid&63, wv = tid>>6;
  const int wr = (wv>>1)*64, wc = (wv&1)*64;
  f32x4 acc[4][4];
  #pragma unroll
  for(int i=0;i<4;i++)
    #pragma unroll
    for(int j=0;j<4;j++) acc[i][j] = (f32x4){0.f,0.f,0.f,0.f};
  for(int kb=0; kb<DDIM; kb+=64){
    __syncthreads();
    #pragma unroll
    for(int p=0;p<4;p++){
      int r = p*32 + (tid>>3), cb = tid&7;
      int off = r*64 + cb*8;
      gload16(A + (size_t)(m0+r)*DDIM + kb + cb*8, sA + off);
      gload16(B + (size_t)(n0+r)*DDIM + kb + cb*8, sB + off);
    }
    __syncthreads();
    #pragma unroll
    for(int ks=0;ks<2;ks++){
      short8 af[4], bfr[4];
      int kk = ks*32 + 8*(lane>>4);
      #pragma unroll
      for(int i=0;i<4;i++){
        af[i]  = frag_lin(sA, wr + i*16 + (lane&15), kk);
        bfr[i] = frag_lin(sB, wc + i*16 + (lane&15), kk);
      }
      #pragma unroll
      for(int i=0;i<4;i++)
        #pragma unroll
        for(int j=0;j<4;j++)
          acc[i][j] = MFMA16(af[i], bfr[j], acc[i][j]);
    }
  }
  const int rb = 4*(lane>>4), cb2 = lane&15;
  #pragma unroll
  for(int i=0;i<4;i++)
    #pragma unroll
    for(int j=0;j<4;j++){
      int col = h*NDIM + n0 + wc + j*16 + cb2;
      #pragma unroll
      for(int r=0;r<4;r++){
        int row = m0 + wr + i*16 + rb + r;
        float v = acc[i][j][r];
        float a = v>0.f ? v*v : 0.f;
        a *= bf2f(xs[(size_t)row*HN + col]);
        xy[(size_t)row*HN + col] = f2bf(a);
      }
    }
}

// ---- phase A (rope + vbT fused): single-pass gate via registers ----
__global__ __launch_bounds__(256) void k_phase_a(const u16* __restrict__ xs, u16* __restrict__ gate,
                          const float* __restrict__ cosT, const float* __restrict__ sinT,
                          u16* __restrict__ qg, float* __restrict__ gle,
                          const u16* __restrict__ xin_bf, u16* __restrict__ vbT){
  __shared__ u16 s[64*DDIM];
  int c = blockIdx.y;
  if(blockIdx.x == 32){
    int tid = threadIdx.x;
    #pragma unroll
    for(int p=0;p<8;p++){
      int idx = p*256+tid; int t = idx>>5, cb = idx&31;
      *(short8*)(s + t*DDIM + cb*8) = *(const short8*)(xin_bf + ((size_t)c*CHK + t)*DDIM + cb*8);
    }
    __syncthreads();
    int d = tid;
    u16 col[64];
    #pragma unroll
    for(int t=0;t<64;t++) col[t] = s[t*DDIM + d];
    u16* dst = vbT + ((size_t)c*DDIM + d)*CHK;
    #pragma unroll
    for(int p=0;p<8;p++){
      short8 v;
      #pragma unroll
      for(int e=0;e<8;e++) v[e] = (short)col[p*8+e];
      *(short8*)(dst + p*8) = v;
    }
    return;
  }
  int j = blockIdx.x*256 + threadIdx.x;
  int cc = j & 255;
  int ci = cc & 127;
  bool hi_ = cc >= 128;
  int poff = hi_ ? -128 : 128;
  size_t base = (size_t)c*CHK*HN + j;
  u16 gv[64];
  float gsum = 0.f;
  #pragma unroll
  for(int t=0;t<CHK;t++){ gv[t] = gate[base + (size_t)t*HN]; gsum -= bf2f(gv[t]); }
  float egsum = expf(gsum);
  float gc = 0.f;
  #pragma unroll
  for(int t=0;t<CHK;t++){
    size_t ix = base + (size_t)t*HN;
    gc -= bf2f(gv[t]);
    int tt = c*CHK + t;
    float own = bf2f(xs[ix]), oth = bf2f(xs[ix + poff]);
    float cs = cosT[tt*128+ci], sn = sinT[tt*128+ci];
    float qv = hi_ ? (own*cs + oth*sn) : (own*cs - oth*sn);
    float e1 = expf(gc);
    qg[ix] = f2bf(qv * e1 * SCALE_Q);
    gate[ix] = f2bf(qv / e1);       // kg in-place
  }
  gle[(size_t)c*HN + j] = egsum;
}

// ---- merged QK^T partials + state chain (both READ kg; ST is a disjoint buffer) ----
__global__ __launch_bounds__(256) void k_qk_state(
  const u16* __restrict__ qg, const u16* __restrict__ kg, float* __restrict__ Apart,
  const u16* __restrict__ vbT, const float* __restrict__ gle, u16* __restrict__ ST){
  __shared__ __align__(16) u16 smem[16384];   // 32 KB union
  int bid = blockIdx.x;
  int tid = threadIdx.x, lane = tid&63, wv = tid>>6;
  if(bid < 256){
    int c = bid&15, h = (bid>>4)&3, kz = bid>>6;
    const u16* qb = qg + (size_t)c*CHK*HN + h*NDIM + kz*512;
    const u16* kb = kg + (size_t)c*CHK*HN + h*NDIM + kz*512;
    f32x4 acc[4];
    #pragma unroll
    for(int j=0;j<4;j++) acc[j] = (f32x4){0.f,0.f,0.f,0.f};
    #pragma unroll
    for(int p=0;p<2;p++){
      int r = p*32 + (tid>>3), cb = tid&7;
      int off = r*64 + cb*8;
      gload16(qb + (size_t)r*HN + cb*8, smem + off);
      gload16(kb + (size_t)r*HN + cb*8, smem + 8192 + off);
    }
    __syncthreads();
    for(int kt=0; kt<8; kt++){
      int curo = (kt&1)*4096, nxto = ((kt+1)&1)*4096;
      if(kt<7){
        #pragma unroll
        for(int p=0;p<2;p++){
          int r = p*32 + (tid>>3), cb = tid&7;
          int off = r*64 + cb*8;
          gload16(qb + (kt+1)*64 + (size_t)r*HN + cb*8, smem + nxto + off);
          gload16(kb + (kt+1)*64 + (size_t)r*HN + cb*8, smem + 8192 + nxto + off);
        }
      }
      #pragma unroll
      for(int kh=0;kh<2;kh++){
        int kk = kh*32 + 8*(lane>>4);
        short8 af = frag_lin(smem + curo, wv*16 + (lane&15), kk);
        #pragma unroll
        for(int j=0;j<4;j++){
          short8 b = frag_lin(smem + 8192 + curo, j*16 + (lane&15), kk);
          acc[j] = MFMA16(af, b, acc[j]);
        }
      }
      __syncthreads();
    }
    int rb = 4*(lane>>4), cl = lane&15;
    float* ab = Apart + (size_t)kz*(NCH*NH_*4096) + ((size_t)c*NH_+h)*4096;
    #pragma unroll
    for(int j=0;j<4;j++)
      #pragma unroll
      for(int r=0;r<4;r++){
        int t = wv*16 + rb + r, s = j*16 + cl;
        ab[t*64 + s] = acc[j][r];
      }
  } else {
    int idx = bid - 256;
    int nb = idx&63, db = (idx>>6)&3, h = idx>>8;
    int ng = nb*32;
    int r8a = tid>>3, cb = tid&7;
    int tr = tid>>2, tseg = tid&3;
    f32x4 S[2];
    S[0] = (f32x4){0.f,0.f,0.f,0.f}; S[1] = (f32x4){0.f,0.f,0.f,0.f};
    short8 kreg = *(const short8*)(kg + (size_t)tr*HN + h*NDIM + ng + tseg*8);
    #pragma unroll
    for(int p=0;p<2;p++){
      int r = p*32 + r8a;
      gload16(vbT + ((size_t)0*DDIM + db*64 + r)*CHK + cb*8, smem + 4096 + r*64 + cb*8);
    }
    int cur = 0;
    for(int c=0;c<15;c++){
      #pragma unroll
      for(int e=0;e<8;e++){
        int n = tseg*8 + e;
        *(u16*)((char*)smem + cur*4096 + n*128 + ((tr*2) ^ ((n&7)<<4))) = (u16)kreg[e];
      }
      __syncthreads();
      if(c<14){
        kreg = *(const short8*)(kg + (size_t)((c+1)*CHK + tr)*HN + h*NDIM + ng + tseg*8);
        int nxt = cur^1;
        #pragma unroll
        for(int p=0;p<2;p++){
          int r = p*32 + r8a;
          gload16(vbT + ((size_t)(c+1)*DDIM + db*64 + r)*CHK + cb*8, smem + 4096 + nxt*4096 + r*64 + cb*8);
        }
      }
      #pragma unroll
      for(int kh=0;kh<2;kh++){
        int kk = kh*32 + 8*(lane>>4);
        short8 af = frag_lin(smem + 4096 + cur*4096, wv*16 + (lane&15), kk);
        #pragma unroll
        for(int fn=0;fn<2;fn++){
          short8 b = frag64(smem + cur*2048, fn*16 + (lane&15), kk);
          S[fn] = MFMA16(af, b, S[fn]);
        }
      }
      #pragma unroll
      for(int fn=0;fn<2;fn++){
        float gvl = gle[(size_t)c*HN + h*NDIM + ng + fn*16 + (lane&15)];
        S[fn][0]*=gvl; S[fn][1]*=gvl; S[fn][2]*=gvl; S[fn][3]*=gvl;
      }
      #pragma unroll
      for(int fn=0;fn<2;fn++)
        #pragma unroll
        for(int r=0;r<4;r++){
          int d = wv*16 + 4*(lane>>4) + r, n = fn*16 + (lane&15);
          *(u16*)((char*)(smem + 12288) + d*64 + ((n*2) ^ (((d>>2)&3)<<4))) = f2bf(S[fn][r]);
        }
      __syncthreads();
      {
        int dl = tid>>2, seg = tid&3;
        short8 v = *(const short8*)((const char*)(smem + 12288) + dl*64 + ((seg*16) ^ (((dl>>2)&3)<<4)));
        *(short8*)(ST + (((size_t)c*NH_ + h)*DDIM + db*64 + dl)*NDIM + ng + seg*8) = v;
      }
      cur ^= 1;
    }
  }
}

// ---- fused output, n-split ×2 ----
__global__ __launch_bounds__(256) void k_out(const u16* __restrict__ qg, const u16* __restrict__ ST,
                                             const float* __restrict__ Apart, const u16* __restrict__ vbT,
                                             float* __restrict__ op){
  int c = blockIdx.x, h = blockIdx.y, zz = blockIdx.z;
  int db = zz>>1, nz = zz&1;
  int tid = threadIdx.x, lane = tid&63, wv = tid>>6;
  __shared__ __align__(16) u16 sQ[2][64*64], sS[2][64*64];
  __shared__ __align__(16) u16 sAm[64*64], sV[64*64];
  const u16* stb = (c>0) ? ST + ((size_t)(c-1)*NH_ + h)*DDIM*(size_t)NDIM + (size_t)db*64*NDIM : ST;
  const u16* qb  = qg + (size_t)c*CHK*HN + h*NDIM;
  const int ktA = nz ? 15 : 0, ktB = nz ? 32 : 15;
  int r8a = tid>>3, cb = tid&7;
  f32x4 acc[4];
  #pragma unroll
  for(int j=0;j<4;j++) acc[j] = (f32x4){0.f,0.f,0.f,0.f};
  if(c>0){
    #pragma unroll
    for(int p=0;p<2;p++){
      int r = p*32 + r8a;
      gload16(qb + ktA*64 + (size_t)r*HN + cb*8, sQ[0] + r*64 + cb*8);
      gload16(stb + (size_t)r*NDIM + ktA*64 + cb*8, sS[0] + r*64 + cb*8);
    }
  }
  if(nz==0){
    size_t abase = ((size_t)c*NH_ + h)*4096;
    #pragma unroll
    for(int e=0;e<16;e++){
      int idx = e*256 + tid;
      int t = idx>>6, s = idx&63;
      float sum = Apart[abase + idx]
                + Apart[(size_t)(NCH*NH_*4096)   + abase + idx]
                + Apart[(size_t)(NCH*NH_*4096)*2 + abase + idx]
                + Apart[(size_t)(NCH*NH_*4096)*3 + abase + idx];
      *(u16*)((char*)sAm + t*128 + ((s*2)^((t&7)<<4))) = f2bf((s<=t)? sum : 0.f);
    }
    #pragma unroll
    for(int p=0;p<2;p++){
      int r = p*32 + r8a;
      gload16(vbT + ((size_t)c*DDIM + db*64 + r)*CHK + cb*8, sV + r*64 + cb*8);
    }
  }
  __syncthreads();
  if(nz==0){
    #pragma unroll
    for(int kh=0;kh<2;kh++){
      int kk = kh*32 + 8*(lane>>4);
      short8 af = frag64(sAm, wv*16 + (lane&15), kk);
      #pragma unroll
      for(int j=0;j<4;j++){
        short8 b = frag_lin(sV, j*16 + (lane&15), kk);
        acc[j] = MFMA16(af, b, acc[j]);
      }
    }
  }
  if(c>0){
    int cur = 0;
    for(int kt=ktA; kt<ktB; kt++){
      if(kt+1<ktB){
        #pragma unroll
        for(int p=0;p<2;p++){
          int r = p*32 + r8a;
          gload16(qb + (kt+1)*64 + (size_t)r*HN + cb*8, sQ[cur^1] + r*64 + cb*8);
          gload16(stb + (size_t)r*NDIM + (kt+1)*64 + cb*8, sS[cur^1] + r*64 + cb*8);
        }
      }
      #pragma unroll
      for(int kh=0;kh<2;kh++){
        int kk = kh*32 + 8*(lane>>4);
        short8 af = frag_lin(sQ[cur], wv*16 + (lane&15), kk);
        #pragma unroll
        for(int j=0;j<4;j++){
          short8 b = frag_lin(sS[cur], j*16 + (lane&15), kk);
          acc[j] = MFMA16(af, b, acc[j]);
        }
      }
      __syncthreads();
      cur ^= 1;
    }
  }
  int rb = 4*(lane>>4), cl = lane&15;
  #pragma unroll
  for(int j=0;j<4;j++){
    int d = db*64 + j*16 + cl;
    #pragma unroll
    for(int r=0;r<4;r++){
      int t = c*CHK + wv*16 + rb + r;
      op[((size_t)(nz*NH_ + h)*TLEN + t)*DDIM + d] = acc[j][r];
    }
  }
}

// ---- layernorm over d of op0+op1 -> oln bf16 ----
__global__ __launch_bounds__(256) void k_ln(const float* __restrict__ op, u16* __restrict__ oln){
  __shared__ float tmp[4];
  int t = blockIdx.x, h = blockIdx.y, d = threadIdx.x;
  size_t ix = ((size_t)h*TLEN + t)*DDIM + d;
  float v = op[ix] + op[(size_t)NH_*TLEN*DDIM + ix];
  float s1 = block_sum(v, tmp);
  float m = s1*(1.0f/DDIM);
  float cv = v - m;
  float s2 = block_sum(cv*cv, tmp);
  oln[ix] = f2bf(cv * rsqrtf(s2*(1.0f/DDIM) + 1e-5f));
}

// ---- dec epilogue ----
__global__ __launch_bounds__(256) void k_post(const float* __restrict__ ypart, float* __restrict__ xin,
                                              const float* __restrict__ x0,
                                              const float* rl, const float* xl, const float* bl,
                                              int li, u16* __restrict__ xin_bf, u16* __restrict__ xf){
  __shared__ float tmp[4];
  int t = blockIdx.x, d = threadIdx.x;
  float v = 0.f;
  #pragma unroll
  for(int z=0;z<16;z++) v += ypart[(size_t)z*TLEN*DDIM + t*DDIM + d];
  float s1 = block_sum(v, tmp);
  float m = s1*(1.0f/DDIM);
  float cvt = v - m;
  float s2 = block_sum(cvt*cvt, tmp);
  float y = cvt * rsqrtf(s2*(1.0f/DDIM) + 1e-5f);
  float xn = y + xin[t*DDIM+d];
  float s3 = block_sum(xn*xn, tmp);
  float xv = xn * rsqrtf(s3*(1.0f/DDIM) + 1e-5f);
  if(li<3){
    float xi = rl[li+1]*xv + xl[li+1]*x0[t*DDIM+d];
    xin[t*DDIM+d] = xi; xin_bf[t*DDIM+d] = f2bf(xi);
  } else {
    float fv = xv - bl[0]*x0[t*DDIM+d];
    float s4 = block_sum(fv*fv, tmp);
    xf[t*DDIM+d] = f2bf(fv * rsqrtf(s4*(1.0f/DDIM) + 1e-5f));
  }
}

extern "C" void kernel_launch(void* const* d_in, const int* in_sizes, int n_in,
                              void* d_out, int out_size, void* d_ws, size_t ws_size,
                              hipStream_t stream){
  (void)in_sizes; (void)n_in; (void)out_size; (void)ws_size;
  const float* embed_w = (const float*)d_in[0];
  const float* lm_w    = (const float*)d_in[1];
  const float* enc_w   = (const float*)d_in[2];
  const float* gate_w  = (const float*)d_in[3];
  const float* dec_w   = (const float*)d_in[4];
  const float* encv_w  = (const float*)d_in[5];
  const float* backout = (const float*)d_in[6];
  const float* rlam    = (const float*)d_in[7];
  const float* xlam    = (const float*)d_in[8];
  const int*   idx     = (const int*)d_in[9];
  float* out = (float*)d_out;

  char* p = (char*)d_ws;
  auto alloc = [&](size_t b)->char*{ char* r=p; p += (b+255)&~(size_t)255; return r; };
  float* cosT = (float*)alloc((size_t)TLEN*128*4);
  float* sinT = (float*)alloc((size_t)TLEN*128*4);
  float* x0   = (float*)alloc((size_t)TLEN*DDIM*4);
  float* xin  = (float*)alloc((size_t)TLEN*DDIM*4);
  u16* xin_bf = (u16*)alloc((size_t)TLEN*DDIM*2);
  u16* xs     = (u16*)alloc((size_t)TLEN*HN*2);        // dec partials alias this
  u16* q      = (u16*)alloc((size_t)TLEN*HN*2);        // qg, later xy
  u16* gate   = (u16*)alloc((size_t)TLEN*HN*2);        // gate -> kg in-place; dead after k_qk_state
  u16* ST     = (u16*)alloc((size_t)15*NH_*DDIM*NDIM*2); // 62.9 MB dedicated
  float* ypart= (float*)xs; // live dec..post (xs dead)
  float* gle  = (float*)alloc((size_t)NCH*HN*4);
  u16* vbT    = (u16*)alloc((size_t)NCH*DDIM*CHK*2);
  float* Apart= (float*)alloc((size_t)4*NCH*NH_*CHK*CHK*4);
  float* op   = (float*)alloc((size_t)2*NH_*TLEN*DDIM*4);
  u16* oln    = (u16*)alloc((size_t)NH_*TLEN*DDIM*2);
  u16* xf     = (u16*)alloc((size_t)TLEN*DDIM*2);
  u16* w_enc  = (u16*)alloc((size_t)HN*DDIM*2);
  u16* w_gate = (u16*)alloc((size_t)HN*DDIM*2);
  u16* w_dec  = (u16*)alloc((size_t)DDIM*HN*2);
  u16* w_encv = (u16*)alloc((size_t)NH_*NDIM*DDIM*2);

  k_setup<<<6144,256,0,stream>>>(embed_w, idx, rlam, xlam,
                                 enc_w, gate_w, dec_w, encv_w,
                                 w_enc, w_gate, w_dec, w_encv,
                                 cosT, sinT, x0, xin, xin_bf);

  for(int li=0; li<4; li++){
    k_gemm_eg<<<dim3(8,128),256,0,stream>>>(xin_bf,w_enc,w_gate,xs,gate);
    k_phase_a<<<dim3(33,NCH),256,0,stream>>>(xs,gate,cosT,sinT,/*qg=*/q,gle,xin_bf,vbT);
    k_qk_state<<<1280,256,0,stream>>>(/*qg=*/q,/*kg=*/gate,Apart,vbT,gle,ST);  // qk ∥ state
    k_out<<<dim3(NCH,NH_,8),256,0,stream>>>(/*qg=*/q,ST,Apart,vbT,op);
    k_ln<<<dim3(TLEN,NH_),256,0,stream>>>(op,oln);
    k_gemm_ys<<<dim3(8,16,NH_),256,0,stream>>>(oln,w_encv,xs,/*xy=*/q);   // last read of xs
    k_gemm<true><<<dim3(8,2,16),256,0,stream>>>(q,HN,w_dec,HN,ypart,DDIM,512); // writes over xs
    k_post<<<TLEN,256,0,stream>>>(ypart,xin,x0,rlam,xlam,backout,li,xin_bf,xf);
  }
  k_gemm_lm<<<393,256,0,stream>>>(xf, lm_w, out);
}

// Round 15
// 634.472 us; speedup vs baseline: 1.3946x; 1.0044x over previous
//
#include <hip/hip_runtime.h>
#include <math.h>

#define TLEN 1024
#define DDIM 256
#define NH_  4
#define NDIM 2048
#define HN   8192
#define NCH  16
#define CHK  64
#define VP_  50304
#define SCALE_Q 0.022097086912079608f  // 2048^-0.5

typedef unsigned short u16;
typedef __attribute__((ext_vector_type(8))) short short8;
typedef __attribute__((ext_vector_type(4))) float f32x4;

#define MFMA16(a,b,c) __builtin_amdgcn_mfma_f32_16x16x32_bf16((a),(b),(c),0,0,0)

__device__ __forceinline__ float bf2f(u16 u){ return __uint_as_float(((unsigned)u)<<16); }
__device__ __forceinline__ u16 f2bf(float f){
  unsigned x = __float_as_uint(f);
  return (u16)((x + 0x7fffu + ((x>>16)&1u)) >> 16);
}
__device__ __forceinline__ float wave_sum(float v){
  #pragma unroll
  for(int o=1;o<64;o<<=1) v += __shfl_xor(v,o,64);
  return v;
}
__device__ __forceinline__ float block_sum(float v, float* tmp){
  v = wave_sum(v);
  __syncthreads();
  if((threadIdx.x&63)==0) tmp[threadIdx.x>>6]=v;
  __syncthreads();
  return tmp[0]+tmp[1]+tmp[2]+tmp[3];
}

// ---- async global->LDS staging (linear LDS layout, 16B/lane) ----
__device__ __forceinline__ void gload16(const u16* g, u16* l){
  __builtin_amdgcn_global_load_lds((const __attribute__((address_space(1))) unsigned int*)g,
                                   (__attribute__((address_space(3))) unsigned int*)l, 16, 0, 0);
}
__device__ __forceinline__ short8 frag_lin(const u16* lds, int row, int k){
  return *(const short8*)((const char*)lds + row*128 + k*2);
}
// swizzled reads (for ds_write-staged tiles)
__device__ __forceinline__ short8 frag64(const u16* lds, int row, int k){
  return *(const short8*)((const char*)lds + row*128 + ((k*2) ^ ((row&7)<<4)));
}
__device__ __forceinline__ short8 frag512(const u16* lds, int row, int k){
  return *(const short8*)((const char*)lds + row*512 + ((k*2) ^ ((row&7)<<4)));
}

// ---- merged setup: rope tables + weight cvt + embed/rmsnorm/xin0 ----
__global__ __launch_bounds__(256) void k_setup(
  const float* __restrict__ emb, const int* __restrict__ idx,
  const float* rl, const float* xl,
  const float* __restrict__ enc_w, const float* __restrict__ gate_w,
  const float* __restrict__ dec_w, const float* __restrict__ encv_w,
  u16* w_enc, u16* w_gate, u16* w_dec, u16* w_encv,
  float* cosT, float* sinT, float* x0, float* xin, u16* xin_bf){
  __shared__ float tmp[4];
  int bid = blockIdx.x, tid = threadIdx.x;
  if(bid < 1024){
    if(tid < 128){
      int t = bid, i = tid;
      float inv_freq = exp2f(-18.0f * (float)(2*i) * (1.0f/256.0f));
      float fr = (float)t * inv_freq;
      float xsc = ((float)(2*i) + 102.4f) * (1.0f/358.4f);
      float power = ((float)t - 512.0f) * (1.0f/512.0f);
      float sc = exp2f(power * log2f(xsc));
      cosT[t*128+i] = cosf(fr)*sc;
      sinT[t*128+i] = sinf(fr)*sc;
    }
  } else if(bid < 5120){
    size_t base = (size_t)(bid-1024)*2048 + tid;
    #pragma unroll
    for(int k=0;k<8;k++){
      size_t i = base + (size_t)k*256;
      int seg = (int)(i>>21); size_t off = i & 2097151;
      const float* s; u16* dst;
      if(seg==0){ s=enc_w; dst=w_enc; } else if(seg==1){ s=gate_w; dst=w_gate; }
      else if(seg==2){ s=dec_w; dst=w_dec; } else { s=encv_w; dst=w_encv; }
      dst[off] = f2bf(s[off]);
    }
  } else {
    int t = bid - 5120, d = tid;
    float v = emb[(size_t)idx[t]*DDIM + d];
    float s = block_sum(v*v, tmp);
    float o = v * rsqrtf(s*(1.0f/DDIM) + 1e-5f);
    x0[t*DDIM+d] = o;
    float xi = rl[0]*o + xl[0]*o;
    xin[t*DDIM+d] = xi; xin_bf[t*DDIM+d] = f2bf(xi);
  }
}

// ---- generic bf16 GEMM: C = A @ B^T fp32; SPLITK -> per-z partial buffer ----
template<bool SPLITK>
__global__ __launch_bounds__(256) void k_gemm(
  const u16* __restrict__ A, int lda, const u16* __restrict__ B, int ldb,
  float* __restrict__ C, int ldc, int kchunk)
{
  __shared__ __align__(16) u16 sA[128*64];
  __shared__ __align__(16) u16 sB[128*64];
  const int m0 = blockIdx.x*128, n0 = blockIdx.y*128;
  const int k0 = blockIdx.z*kchunk;
  const int tid = threadIdx.x, lane = tid&63, wv = tid>>6;
  const int wr = (wv>>1)*64, wc = (wv&1)*64;
  f32x4 acc[4][4];
  #pragma unroll
  for(int i=0;i<4;i++)
    #pragma unroll
    for(int j=0;j<4;j++) acc[i][j] = (f32x4){0.f,0.f,0.f,0.f};
  for(int kb=0; kb<kchunk; kb+=64){
    __syncthreads();
    #pragma unroll
    for(int p=0;p<4;p++){
      int r = p*32 + (tid>>3), cb = tid&7;
      int off = r*64 + cb*8;
      gload16(A + (size_t)(m0+r)*lda + k0+kb + cb*8, sA + off);
      gload16(B + (size_t)(n0+r)*ldb + k0+kb + cb*8, sB + off);
    }
    __syncthreads();
    #pragma unroll
    for(int ks=0;ks<2;ks++){
      short8 af[4], bfr[4];
      int kk = ks*32 + 8*(lane>>4);
      #pragma unroll
      for(int i=0;i<4;i++){
        af[i]  = frag_lin(sA, wr + i*16 + (lane&15), kk);
        bfr[i] = frag_lin(sB, wc + i*16 + (lane&15), kk);
      }
      #pragma unroll
      for(int i=0;i<4;i++)
        #pragma unroll
        for(int j=0;j<4;j++)
          acc[i][j] = MFMA16(af[i], bfr[j], acc[i][j]);
    }
  }
  size_t poff = SPLITK ? (size_t)blockIdx.z * (size_t)gridDim.x * 128 * ldc : 0;
  const int rb = 4*(lane>>4), cb2 = lane&15;
  #pragma unroll
  for(int i=0;i<4;i++)
    #pragma unroll
    for(int j=0;j<4;j++){
      int col = n0 + wc + j*16 + cb2;
      #pragma unroll
      for(int r=0;r<4;r++){
        int row = m0 + wr + i*16 + rb + r;
        C[poff + (size_t)row*ldc + col] = acc[i][j][r];
      }
    }
}

// ---- lm GEMM: one block per 128-col B panel; B fp32->bf16 LDS once; loop 8 M-tiles ----
__global__ __launch_bounds__(256) void k_gemm_lm(
  const u16* __restrict__ A, const float* __restrict__ Bf, float* __restrict__ C)
{
  __shared__ __align__(16) u16 sB[128*256];   // 64 KB, 512B rows, swizzled
  __shared__ __align__(16) u16 sA[128*64];    // 16 KB
  const int n0 = blockIdx.x*128;
  const int tid = threadIdx.x, lane = tid&63, wv = tid>>6;
  const int wr = (wv>>1)*64, wc = (wv&1)*64;
  {
    int n = tid>>1, half = tid&1;
    const float* bp = Bf + (size_t)(n0+n)*DDIM + half*128;
    #pragma unroll
    for(int s=0;s<16;s++){
      f32x4 v0 = *(const f32x4*)(bp + s*8);
      f32x4 v1 = *(const f32x4*)(bp + s*8 + 4);
      short8 w;
      #pragma unroll
      for(int e=0;e<4;e++){ w[e]=(short)f2bf(v0[e]); w[e+4]=(short)f2bf(v1[e]); }
      int k0 = half*128 + s*8;
      *(short8*)((char*)sB + n*512 + ((k0*2) ^ ((n&7)<<4))) = w;
    }
  }
  for(int mi=0; mi<8; mi++){
    int m0 = mi*128;
    f32x4 acc[4][4];
    #pragma unroll
    for(int i=0;i<4;i++)
      #pragma unroll
      for(int j=0;j<4;j++) acc[i][j] = (f32x4){0.f,0.f,0.f,0.f};
    for(int kb=0; kb<4; kb++){
      __syncthreads();
      #pragma unroll
      for(int p=0;p<4;p++){
        int r = p*32 + (tid>>3), cb = tid&7;
        gload16(A + (size_t)(m0+r)*DDIM + kb*64 + cb*8, sA + r*64 + cb*8);
      }
      __syncthreads();
      #pragma unroll
      for(int ks=0;ks<2;ks++){
        short8 af[4], bfr[4];
        int kk = ks*32 + 8*(lane>>4);
        #pragma unroll
        for(int i=0;i<4;i++){
          af[i]  = frag_lin(sA, wr + i*16 + (lane&15), kk);
          bfr[i] = frag512(sB, wc + i*16 + (lane&15), kb*64 + kk);
        }
        #pragma unroll
        for(int i=0;i<4;i++)
          #pragma unroll
          for(int j=0;j<4;j++)
            acc[i][j] = MFMA16(af[i], bfr[j], acc[i][j]);
      }
    }
    const int rb = 4*(lane>>4), cb2 = lane&15;
    #pragma unroll
    for(int i=0;i<4;i++)
      #pragma unroll
      for(int j=0;j<4;j++){
        int col = n0 + wc + j*16 + cb2;
        #pragma unroll
        for(int r=0;r<4;r++){
          int row = m0 + wr + i*16 + rb + r;
          C[(size_t)row*VP_ + col] = acc[i][j][r];
        }
      }
  }
}

// ---- fused enc+gate GEMM (128x128 tile, high TLP; B is L2-resident) ----
__global__ __launch_bounds__(256) void k_gemm_eg(
  const u16* __restrict__ xin_bf, const u16* __restrict__ w_enc, const u16* __restrict__ w_gate,
  u16* __restrict__ xs, u16* __restrict__ gate)
{
  __shared__ __align__(16) u16 sA[128*64];
  __shared__ __align__(16) u16 sB[128*64];
  const int yy = blockIdx.y;
  const bool isg = yy >= 64;
  const u16* B = isg ? w_gate : w_enc;
  u16* C = isg ? gate : xs;
  const float mul = isg ? (1.0f/1024.0f) : 1.0f;
  const int m0 = blockIdx.x*128, n0 = (yy&63)*128;
  const int tid = threadIdx.x, lane = tid&63, wv = tid>>6;
  const int wr = (wv>>1)*64, wc = (wv&1)*64;
  f32x4 acc[4][4];
  #pragma unroll
  for(int i=0;i<4;i++)
    #pragma unroll
    for(int j=0;j<4;j++) acc[i][j] = (f32x4){0.f,0.f,0.f,0.f};
  for(int kb=0; kb<DDIM; kb+=64){
    __syncthreads();
    #pragma unroll
    for(int p=0;p<4;p++){
      int r = p*32 + (tid>>3), cb = tid&7;
      int off = r*64 + cb*8;
      gload16(xin_bf + (size_t)(m0+r)*DDIM + kb + cb*8, sA + off);
      gload16(B + (size_t)(n0+r)*DDIM + kb + cb*8, sB + off);
    }
    __syncthreads();
    #pragma unroll
    for(int ks=0;ks<2;ks++){
      short8 af[4], bfr[4];
      int kk = ks*32 + 8*(lane>>4);
      #pragma unroll
      for(int i=0;i<4;i++){
        af[i]  = frag_lin(sA, wr + i*16 + (lane&15), kk);
        bfr[i] = frag_lin(sB, wc + i*16 + (lane&15), kk);
      }
      #pragma unroll
      for(int i=0;i<4;i++)
        #pragma unroll
        for(int j=0;j<4;j++)
          acc[i][j] = MFMA16(af[i], bfr[j], acc[i][j]);
    }
  }
  const int rb = 4*(lane>>4), cb2 = lane&15;
  #pragma unroll
  for(int i=0;i<4;i++)
    #pragma unroll
    for(int j=0;j<4;j++){
      int col = n0 + wc + j*16 + cb2;
      #pragma unroll
      for(int r=0;r<4;r++){
        int row = m0 + wr + i*16 + rb + r;
        float v = acc[i][j][r];
        float a = v>0.f ? v*v*mul : 0.f;
        C[(size_t)row*HN + col] = f2bf(a);
      }
    }
}

// ---- ys GEMM, batched over heads ----
__global__ __launch_bounds__(256) void k_gemm_ys(
  const u16* __restrict__ olnp, const u16* __restrict__ wvp,
  const u16* __restrict__ xs, u16* __restrict__ xy)
{
  __shared__ __align__(16) u16 sA[128*64];
  __shared__ __align__(16) u16 sB[128*64];
  const int m0 = blockIdx.x*128, n0 = blockIdx.y*128, h = blockIdx.z;
  const u16* A = olnp + (size_t)h*TLEN*DDIM;
  const u16* B = wvp  + (size_t)h*NDIM*DDIM;
  const int tid = threadIdx.x, lane = tid&63, wv = tid>>6;
  const int wr = (wv>>1)*64, wc = (wv&1)*64;
  f32x4 acc[4][4];
  #pragma unroll
  for(int i=0;i<4;i++)
    #pragma unroll
    for(int j=0;j<4;j++) acc[i][j] = (f32x4){0.f,0.f,0.f,0.f};
  for(int kb=0; kb<DDIM; kb+=64){
    __syncthreads();
    #pragma unroll
    for(int p=0;p<4;p++){
      int r = p*32 + (tid>>3), cb = tid&7;
      int off = r*64 + cb*8;
      gload16(A + (size_t)(m0+r)*DDIM + kb + cb*8, sA + off);
      gload16(B + (size_t)(n0+r)*DDIM + kb + cb*8, sB + off);
    }
    __syncthreads();
    #pragma unroll
    for(int ks=0;ks<2;ks++){
      short8 af[4], bfr[4];
      int kk = ks*32 + 8*(lane>>4);
      #pragma unroll
      for(int i=0;i<4;i++){
        af[i]  = frag_lin(sA, wr + i*16 + (lane&15), kk);
        bfr[i] = frag_lin(sB, wc + i*16 + (lane&15), kk);
      }
      #pragma unroll
      for(int i=0;i<4;i++)
        #pragma unroll
        for(int j=0;j<4;j++)
          acc[i][j] = MFMA16(af[i], bfr[j], acc[i][j]);
    }
  }
  const int rb = 4*(lane>>4), cb2 = lane&15;
  #pragma unroll
  for(int i=0;i<4;i++)
    #pragma unroll
    for(int j=0;j<4;j++){
      int col = h*NDIM + n0 + wc + j*16 + cb2;
      #pragma unroll
      for(int r=0;r<4;r++){
        int row = m0 + wr + i*16 + rb + r;
        float v = acc[i][j][r];
        float a = v>0.f ? v*v : 0.f;
        a *= bf2f(xs[(size_t)row*HN + col]);
        xy[(size_t)row*HN + col] = f2bf(a);
      }
    }
}

// ---- phase A (rope + vbT fused): single-pass gate via registers ----
__global__ __launch_bounds__(256) void k_phase_a(const u16* __restrict__ xs, u16* __restrict__ gate,
                          const float* __restrict__ cosT, const float* __restrict__ sinT,
                          u16* __restrict__ qg, float* __restrict__ gle,
                          const u16* __restrict__ xin_bf, u16* __restrict__ vbT){
  __shared__ u16 s[64*DDIM];
  int c = blockIdx.y;
  if(blockIdx.x == 32){
    int tid = threadIdx.x;
    #pragma unroll
    for(int p=0;p<8;p++){
      int idx = p*256+tid; int t = idx>>5, cb = idx&31;
      *(short8*)(s + t*DDIM + cb*8) = *(const short8*)(xin_bf + ((size_t)c*CHK + t)*DDIM + cb*8);
    }
    __syncthreads();
    int d = tid;
    u16 col[64];
    #pragma unroll
    for(int t=0;t<64;t++) col[t] = s[t*DDIM + d];
    u16* dst = vbT + ((size_t)c*DDIM + d)*CHK;
    #pragma unroll
    for(int p=0;p<8;p++){
      short8 v;
      #pragma unroll
      for(int e=0;e<8;e++) v[e] = (short)col[p*8+e];
      *(short8*)(dst + p*8) = v;
    }
    return;
  }
  int j = blockIdx.x*256 + threadIdx.x;
  int cc = j & 255;
  int ci = cc & 127;
  bool hi_ = cc >= 128;
  int poff = hi_ ? -128 : 128;
  size_t base = (size_t)c*CHK*HN + j;
  u16 gv[64];
  float gsum = 0.f;
  #pragma unroll
  for(int t=0;t<CHK;t++){ gv[t] = gate[base + (size_t)t*HN]; gsum -= bf2f(gv[t]); }
  float egsum = expf(gsum);
  float gc = 0.f;
  #pragma unroll
  for(int t=0;t<CHK;t++){
    size_t ix = base + (size_t)t*HN;
    gc -= bf2f(gv[t]);
    int tt = c*CHK + t;
    float own = bf2f(xs[ix]), oth = bf2f(xs[ix + poff]);
    float cs = cosT[tt*128+ci], sn = sinT[tt*128+ci];
    float qv = hi_ ? (own*cs + oth*sn) : (own*cs - oth*sn);
    float e1 = expf(gc);
    qg[ix] = f2bf(qv * e1 * SCALE_Q);
    gate[ix] = f2bf(qv / e1);       // kg in-place
  }
  gle[(size_t)c*HN + j] = egsum;
}

// ---- merged QK^T partials + state chain (both READ kg; ST is a disjoint buffer) ----
// Apart stored bf16: halves the 4x-redundant reduce traffic in k_out.
__global__ __launch_bounds__(256) void k_qk_state(
  const u16* __restrict__ qg, const u16* __restrict__ kg, u16* __restrict__ Apart,
  const u16* __restrict__ vbT, const float* __restrict__ gle, u16* __restrict__ ST){
  __shared__ __align__(16) u16 smem[16384];   // 32 KB union
  int bid = blockIdx.x;
  int tid = threadIdx.x, lane = tid&63, wv = tid>>6;
  if(bid < 256){
    int c = bid&15, h = (bid>>4)&3, kz = bid>>6;
    const u16* qb = qg + (size_t)c*CHK*HN + h*NDIM + kz*512;
    const u16* kb = kg + (size_t)c*CHK*HN + h*NDIM + kz*512;
    f32x4 acc[4];
    #pragma unroll
    for(int j=0;j<4;j++) acc[j] = (f32x4){0.f,0.f,0.f,0.f};
    #pragma unroll
    for(int p=0;p<2;p++){
      int r = p*32 + (tid>>3), cb = tid&7;
      int off = r*64 + cb*8;
      gload16(qb + (size_t)r*HN + cb*8, smem + off);
      gload16(kb + (size_t)r*HN + cb*8, smem + 8192 + off);
    }
    __syncthreads();
    for(int kt=0; kt<8; kt++){
      int curo = (kt&1)*4096, nxto = ((kt+1)&1)*4096;
      if(kt<7){
        #pragma unroll
        for(int p=0;p<2;p++){
          int r = p*32 + (tid>>3), cb = tid&7;
          int off = r*64 + cb*8;
          gload16(qb + (kt+1)*64 + (size_t)r*HN + cb*8, smem + nxto + off);
          gload16(kb + (kt+1)*64 + (size_t)r*HN + cb*8, smem + 8192 + nxto + off);
        }
      }
      #pragma unroll
      for(int kh=0;kh<2;kh++){
        int kk = kh*32 + 8*(lane>>4);
        short8 af = frag_lin(smem + curo, wv*16 + (lane&15), kk);
        #pragma unroll
        for(int j=0;j<4;j++){
          short8 b = frag_lin(smem + 8192 + curo, j*16 + (lane&15), kk);
          acc[j] = MFMA16(af, b, acc[j]);
        }
      }
      __syncthreads();
    }
    int rb = 4*(lane>>4), cl = lane&15;
    u16* ab = Apart + (size_t)kz*(NCH*NH_*4096) + ((size_t)c*NH_+h)*4096;
    #pragma unroll
    for(int j=0;j<4;j++)
      #pragma unroll
      for(int r=0;r<4;r++){
        int t = wv*16 + rb + r, s = j*16 + cl;
        ab[t*64 + s] = f2bf(acc[j][r]);
      }
  } else {
    int idx = bid - 256;
    int nb = idx&63, db = (idx>>6)&3, h = idx>>8;
    int ng = nb*32;
    int r8a = tid>>3, cb = tid&7;
    int tr = tid>>2, tseg = tid&3;
    f32x4 S[2];
    S[0] = (f32x4){0.f,0.f,0.f,0.f}; S[1] = (f32x4){0.f,0.f,0.f,0.f};
    short8 kreg = *(const short8*)(kg + (size_t)tr*HN + h*NDIM + ng + tseg*8);
    #pragma unroll
    for(int p=0;p<2;p++){
      int r = p*32 + r8a;
      gload16(vbT + ((size_t)0*DDIM + db*64 + r)*CHK + cb*8, smem + 4096 + r*64 + cb*8);
    }
    int cur = 0;
    for(int c=0;c<15;c++){
      #pragma unroll
      for(int e=0;e<8;e++){
        int n = tseg*8 + e;
        *(u16*)((char*)smem + cur*4096 + n*128 + ((tr*2) ^ ((n&7)<<4))) = (u16)kreg[e];
      }
      __syncthreads();
      if(c<14){
        kreg = *(const short8*)(kg + (size_t)((c+1)*CHK + tr)*HN + h*NDIM + ng + tseg*8);
        int nxt = cur^1;
        #pragma unroll
        for(int p=0;p<2;p++){
          int r = p*32 + r8a;
          gload16(vbT + ((size_t)(c+1)*DDIM + db*64 + r)*CHK + cb*8, smem + 4096 + nxt*4096 + r*64 + cb*8);
        }
      }
      #pragma unroll
      for(int kh=0;kh<2;kh++){
        int kk = kh*32 + 8*(lane>>4);
        short8 af = frag_lin(smem + 4096 + cur*4096, wv*16 + (lane&15), kk);
        #pragma unroll
        for(int fn=0;fn<2;fn++){
          short8 b = frag64(smem + cur*2048, fn*16 + (lane&15), kk);
          S[fn] = MFMA16(af, b, S[fn]);
        }
      }
      #pragma unroll
      for(int fn=0;fn<2;fn++){
        float gvl = gle[(size_t)c*HN + h*NDIM + ng + fn*16 + (lane&15)];
        S[fn][0]*=gvl; S[fn][1]*=gvl; S[fn][2]*=gvl; S[fn][3]*=gvl;
      }
      #pragma unroll
      for(int fn=0;fn<2;fn++)
        #pragma unroll
        for(int r=0;r<4;r++){
          int d = wv*16 + 4*(lane>>4) + r, n = fn*16 + (lane&15);
          *(u16*)((char*)(smem + 12288) + d*64 + ((n*2) ^ (((d>>2)&3)<<4))) = f2bf(S[fn][r]);
        }
      __syncthreads();
      {
        int dl = tid>>2, seg = tid&3;
        short8 v = *(const short8*)((const char*)(smem + 12288) + dl*64 + ((seg*16) ^ (((dl>>2)&3)<<4)));
        *(short8*)(ST + (((size_t)c*NH_ + h)*DDIM + db*64 + dl)*NDIM + ng + seg*8) = v;
      }
      cur ^= 1;
    }
  }
}

// ---- fused output, n-split ×2 (Apart now bf16) ----
__global__ __launch_bounds__(256) void k_out(const u16* __restrict__ qg, const u16* __restrict__ ST,
                                             const u16* __restrict__ Apart, const u16* __restrict__ vbT,
                                             float* __restrict__ op){
  int c = blockIdx.x, h = blockIdx.y, zz = blockIdx.z;
  int db = zz>>1, nz = zz&1;
  int tid = threadIdx.x, lane = tid&63, wv = tid>>6;
  __shared__ __align__(16) u16 sQ[2][64*64], sS[2][64*64];
  __shared__ __align__(16) u16 sAm[64*64], sV[64*64];
  const u16* stb = (c>0) ? ST + ((size_t)(c-1)*NH_ + h)*DDIM*(size_t)NDIM + (size_t)db*64*NDIM : ST;
  const u16* qb  = qg + (size_t)c*CHK*HN + h*NDIM;
  const int ktA = nz ? 15 : 0, ktB = nz ? 32 : 15;
  int r8a = tid>>3, cb = tid&7;
  f32x4 acc[4];
  #pragma unroll
  for(int j=0;j<4;j++) acc[j] = (f32x4){0.f,0.f,0.f,0.f};
  if(c>0){
    #pragma unroll
    for(int p=0;p<2;p++){
      int r = p*32 + r8a;
      gload16(qb + ktA*64 + (size_t)r*HN + cb*8, sQ[0] + r*64 + cb*8);
      gload16(stb + (size_t)r*NDIM + ktA*64 + cb*8, sS[0] + r*64 + cb*8);
    }
  }
  if(nz==0){
    size_t abase = ((size_t)c*NH_ + h)*4096;
    #pragma unroll
    for(int e=0;e<16;e++){
      int idx = e*256 + tid;
      int t = idx>>6, s = idx&63;
      float sum = bf2f(Apart[abase + idx])
                + bf2f(Apart[(size_t)(NCH*NH_*4096)   + abase + idx])
                + bf2f(Apart[(size_t)(NCH*NH_*4096)*2 + abase + idx])
                + bf2f(Apart[(size_t)(NCH*NH_*4096)*3 + abase + idx]);
      *(u16*)((char*)sAm + t*128 + ((s*2)^((t&7)<<4))) = f2bf((s<=t)? sum : 0.f);
    }
    #pragma unroll
    for(int p=0;p<2;p++){
      int r = p*32 + r8a;
      gload16(vbT + ((size_t)c*DDIM + db*64 + r)*CHK + cb*8, sV + r*64 + cb*8);
    }
  }
  __syncthreads();
  if(nz==0){
    #pragma unroll
    for(int kh=0;kh<2;kh++){
      int kk = kh*32 + 8*(lane>>4);
      short8 af = frag64(sAm, wv*16 + (lane&15), kk);
      #pragma unroll
      for(int j=0;j<4;j++){
        short8 b = frag_lin(sV, j*16 + (lane&15), kk);
        acc[j] = MFMA16(af, b, acc[j]);
      }
    }
  }
  if(c>0){
    int cur = 0;
    for(int kt=ktA; kt<ktB; kt++){
      if(kt+1<ktB){
        #pragma unroll
        for(int p=0;p<2;p++){
          int r = p*32 + r8a;
          gload16(qb + (kt+1)*64 + (size_t)r*HN + cb*8, sQ[cur^1] + r*64 + cb*8);
          gload16(stb + (size_t)r*NDIM + (kt+1)*64 + cb*8, sS[cur^1] + r*64 + cb*8);
        }
      }
      #pragma unroll
      for(int kh=0;kh<2;kh++){
        int kk = kh*32 + 8*(lane>>4);
        short8 af = frag_lin(sQ[cur], wv*16 + (lane&15), kk);
        #pragma unroll
        for(int j=0;j<4;j++){
          short8 b = frag_lin(sS[cur], j*16 + (lane&15), kk);
          acc[j] = MFMA16(af, b, acc[j]);
        }
      }
      __syncthreads();
      cur ^= 1;
    }
  }
  int rb = 4*(lane>>4), cl = lane&15;
  #pragma unroll
  for(int j=0;j<4;j++){
    int d = db*64 + j*16 + cl;
    #pragma unroll
    for(int r=0;r<4;r++){
      int t = c*CHK + wv*16 + rb + r;
      op[((size_t)(nz*NH_ + h)*TLEN + t)*DDIM + d] = acc[j][r];
    }
  }
}

// ---- layernorm over d of op0+op1 -> oln bf16 ----
__global__ __launch_bounds__(256) void k_ln(const float* __restrict__ op, u16* __restrict__ oln){
  __shared__ float tmp[4];
  int t = blockIdx.x, h = blockIdx.y, d = threadIdx.x;
  size_t ix = ((size_t)h*TLEN + t)*DDIM + d;
  float v = op[ix] + op[(size_t)NH_*TLEN*DDIM + ix];
  float s1 = block_sum(v, tmp);
  float m = s1*(1.0f/DDIM);
  float cv = v - m;
  float s2 = block_sum(cv*cv, tmp);
  oln[ix] = f2bf(cv * rsqrtf(s2*(1.0f/DDIM) + 1e-5f));
}

// ---- dec epilogue ----
__global__ __launch_bounds__(256) void k_post(const float* __restrict__ ypart, float* __restrict__ xin,
                                              const float* __restrict__ x0,
                                              const float* rl, const float* xl, const float* bl,
                                              int li, u16* __restrict__ xin_bf, u16* __restrict__ xf){
  __shared__ float tmp[4];
  int t = blockIdx.x, d = threadIdx.x;
  float v = 0.f;
  #pragma unroll
  for(int z=0;z<16;z++) v += ypart[(size_t)z*TLEN*DDIM + t*DDIM + d];
  float s1 = block_sum(v, tmp);
  float m = s1*(1.0f/DDIM);
  float cvt = v - m;
  float s2 = block_sum(cvt*cvt, tmp);
  float y = cvt * rsqrtf(s2*(1.0f/DDIM) + 1e-5f);
  float xn = y + xin[t*DDIM+d];
  float s3 = block_sum(xn*xn, tmp);
  float xv = xn * rsqrtf(s3*(1.0f/DDIM) + 1e-5f);
  if(li<3){
    float xi = rl[li+1]*xv + xl[li+1]*x0[t*DDIM+d];
    xin[t*DDIM+d] = xi; xin_bf[t*DDIM+d] = f2bf(xi);
  } else {
    float fv = xv - bl[0]*x0[t*DDIM+d];
    float s4 = block_sum(fv*fv, tmp);
    xf[t*DDIM+d] = f2bf(fv * rsqrtf(s4*(1.0f/DDIM) + 1e-5f));
  }
}

extern "C" void kernel_launch(void* const* d_in, const int* in_sizes, int n_in,
                              void* d_out, int out_size, void* d_ws, size_t ws_size,
                              hipStream_t stream){
  (void)in_sizes; (void)n_in; (void)out_size; (void)ws_size;
  const float* embed_w = (const float*)d_in[0];
  const float* lm_w    = (const float*)d_in[1];
  const float* enc_w   = (const float*)d_in[2];
  const float* gate_w  = (const float*)d_in[3];
  const float* dec_w   = (const float*)d_in[4];
  const float* encv_w  = (const float*)d_in[5];
  const float* backout = (const float*)d_in[6];
  const float* rlam    = (const float*)d_in[7];
  const float* xlam    = (const float*)d_in[8];
  const int*   idx     = (const int*)d_in[9];
  float* out = (float*)d_out;

  char* p = (char*)d_ws;
  auto alloc = [&](size_t b)->char*{ char* r=p; p += (b+255)&~(size_t)255; return r; };
  float* cosT = (float*)alloc((size_t)TLEN*128*4);
  float* sinT = (float*)alloc((size_t)TLEN*128*4);
  float* x0   = (float*)alloc((size_t)TLEN*DDIM*4);
  float* xin  = (float*)alloc((size_t)TLEN*DDIM*4);
  u16* xin_bf = (u16*)alloc((size_t)TLEN*DDIM*2);
  u16* xs     = (u16*)alloc((size_t)TLEN*HN*2);        // dec partials alias this
  u16* q      = (u16*)alloc((size_t)TLEN*HN*2);        // qg, later xy
  u16* gate   = (u16*)alloc((size_t)TLEN*HN*2);        // gate -> kg in-place; dead after k_qk_state
  u16* ST     = (u16*)alloc((size_t)15*NH_*DDIM*NDIM*2); // 62.9 MB dedicated
  float* ypart= (float*)xs; // live dec..post (xs dead)
  float* gle  = (float*)alloc((size_t)NCH*HN*4);
  u16* vbT    = (u16*)alloc((size_t)NCH*DDIM*CHK*2);
  u16* Apart  = (u16*)alloc((size_t)4*NCH*NH_*CHK*CHK*2);   // bf16 partials (2 MB)
  float* op   = (float*)alloc((size_t)2*NH_*TLEN*DDIM*4);
  u16* oln    = (u16*)alloc((size_t)NH_*TLEN*DDIM*2);
  u16* xf     = (u16*)alloc((size_t)TLEN*DDIM*2);
  u16* w_enc  = (u16*)alloc((size_t)HN*DDIM*2);
  u16* w_gate = (u16*)alloc((size_t)HN*DDIM*2);
  u16* w_dec  = (u16*)alloc((size_t)DDIM*HN*2);
  u16* w_encv = (u16*)alloc((size_t)NH_*NDIM*DDIM*2);

  k_setup<<<6144,256,0,stream>>>(embed_w, idx, rlam, xlam,
                                 enc_w, gate_w, dec_w, encv_w,
                                 w_enc, w_gate, w_dec, w_encv,
                                 cosT, sinT, x0, xin, xin_bf);

  for(int li=0; li<4; li++){
    k_gemm_eg<<<dim3(8,128),256,0,stream>>>(xin_bf,w_enc,w_gate,xs,gate);
    k_phase_a<<<dim3(33,NCH),256,0,stream>>>(xs,gate,cosT,sinT,/*qg=*/q,gle,xin_bf,vbT);
    k_qk_state<<<1280,256,0,stream>>>(/*qg=*/q,/*kg=*/gate,Apart,vbT,gle,ST);  // qk ∥ state
    k_out<<<dim3(NCH,NH_,8),256,0,stream>>>(/*qg=*/q,ST,Apart,vbT,op);
    k_ln<<<dim3(TLEN,NH_),256,0,stream>>>(op,oln);
    k_gemm_ys<<<dim3(8,16,NH_),256,0,stream>>>(oln,w_encv,xs,/*xy=*/q);   // last read of xs
    k_gemm<true><<<dim3(8,2,16),256,0,stream>>>(q,HN,w_dec,HN,ypart,DDIM,512); // writes over xs
    k_post<<<TLEN,256,0,stream>>>(ypart,xin,x0,rlam,xlam,backout,li,xin_bf,xf);
  }
  k_gemm_lm<<<393,256,0,stream>>>(xf, lm_w, out);
}